// Round 11
// baseline (429.606 us; speedup 1.0000x reference)
//
#include <hip/hip_runtime.h>
#include <hip/hip_bf16.h>
#include <math.h>

#define B_    16
#define L_    2048
#define H_    512
#define NT_   8
#define OUT_  1032
#define HEAD_ 256
#define CH_   16
#define CL_   (L_/CH_)   // 128
#define NWS_  1152       // AT row stride in shorts (z|h then S|PP in place)
#define KP2_  1088       // head GEMM K (17 x 64)

// k5 A-LDS geometry: 32 rows, 136 chunks of 16B (2176B row), XOR-swizzled
#define ACH_  136
#define ASTR_ (ACH_*8)   // shorts per row = 1088
#define RB5_  32         // rows per k5 block

typedef short bf16x8 __attribute__((ext_vector_type(8)));
typedef float f32x4  __attribute__((ext_vector_type(4)));

__device__ __forceinline__ float b2f(unsigned short u) {
    union { unsigned int u32; float f; } v; v.u32 = ((unsigned int)u) << 16; return v.f;
}
__device__ __forceinline__ unsigned short f2b(float f) {
    __hip_bfloat16 h = __float2bfloat16(f);
    return *reinterpret_cast<unsigned short*>(&h);
}
__device__ __forceinline__ float sigmoid_f(float x) {
    return 1.f / (1.f + exp2f(-1.44269504f * x));
}
__device__ __forceinline__ float tanh_f(float x) {
    float e = exp2f(2.88539008f * x);
    return 1.f - 2.f / (e + 1.f);
}
__device__ __forceinline__ float gelu_f(float g) {
    float u  = 0.70710678118654752f * g;
    float ax = fabsf(u);
    float t  = 1.f / (1.f + 0.3275911f * ax);
    float poly = ((((1.061405429f*t - 1.453152027f)*t + 1.421413741f)*t
                   - 0.284496736f)*t + 0.254829592f)*t;
    float e  = exp2f(-1.44269504f * ax * ax);
    float er = 1.f - poly * e;
    er = (u < 0.f) ? -er : er;
    return 0.5f * g * (1.f + er);
}

// ---------------------------------------------------------------------------
// kT: transpose + f32->bf16. in f32 [R][C] -> out bf16 [C][RP], zero r>=R.
// ---------------------------------------------------------------------------
__global__ __launch_bounds__(256) void kT(const float* __restrict__ in,
                                          unsigned short* __restrict__ out,
                                          int R, int C, int RP)
{
    __shared__ float tile[32][33];
    int c0 = blockIdx.x * 32, r0 = blockIdx.y * 32;
    int tx = threadIdx.x & 31, ty = threadIdx.x >> 5;
    #pragma unroll
    for (int j = 0; j < 32; j += 8) {
        int r = r0 + ty + j, c = c0 + tx;
        tile[ty + j][tx] = (r < R && c < C) ? in[(size_t)r*C + c] : 0.f;
    }
    __syncthreads();
    #pragma unroll
    for (int j = 0; j < 32; j += 8) {
        int c = c0 + ty + j, r = r0 + tx;
        if (c < C && r < RP) out[(size_t)c*RP + r] = f2b(tile[tx][ty + j]);
    }
}

// ---------------------------------------------------------------------------
// kP: pack Wg1 (f32 [OUT_][256]) into MFMA B-fragment chunks, 34 K-blocks:
// P[kb*1024 + c*4 + kg] = bf16 Wg1[kb*32+kg*8 .. +8][c]  (zero for k>=OUT_)
// ---------------------------------------------------------------------------
__global__ __launch_bounds__(256) void kP(const float* __restrict__ Wg1,
                                          uint4* __restrict__ P)
{
    int idx = blockIdx.x*256 + threadIdx.x;
    if (idx >= 34*1024) return;
    int kb = idx >> 10;
    int rem = idx & 1023;
    int c  = rem >> 2;
    int kg = rem & 3;
    int k0 = kb*32 + kg*8;
    unsigned short o[8];
    #pragma unroll
    for (int j = 0; j < 8; j++) {
        int k = k0 + j;
        o[j] = (k < OUT_) ? f2b(Wg1[(size_t)k*HEAD_ + c]) : (unsigned short)0;
    }
    P[idx] = *(const uint4*)o;
}

// ---------------------------------------------------------------------------
// K1 (per-dir): t_enc MLP + inp = xc @ Wp + bp. wave-per-row.
// ---------------------------------------------------------------------------
__global__ __launch_bounds__(256) void k1_tenc_inp(
    const float* __restrict__ x, const float* __restrict__ t,
    const float* __restrict__ Wt1, const float* __restrict__ bt1,
    const float* __restrict__ Wt2, const float* __restrict__ bt2,
    const float* __restrict__ Wp, const float* __restrict__ bp,
    float* __restrict__ t_enc,
    unsigned short* __restrict__ inp)
{
    int wv = threadIdx.x >> 6, lane = threadIdx.x & 63;
    size_t row = (size_t)blockIdx.x*4 + wv;
    float tv = t[row];
    float r1[NT_], te[NT_];
    #pragma unroll
    for (int k = 0; k < NT_; k++) r1[k] = fmaxf(tv*Wt1[k] + bt1[k], 0.f);
    #pragma unroll
    for (int j = 0; j < NT_; j++) {
        float a = bt2[j];
        #pragma unroll
        for (int k = 0; k < NT_; k++) a = fmaf(r1[k], Wt2[k*NT_+j], a);
        te[j] = a;
    }
    if (lane < NT_) t_enc[row*NT_ + lane] = te[lane];
    float x0 = x[row*2+0], x1 = x[row*2+1];
    int c0 = lane*8;
    float af[8];
    #pragma unroll
    for (int j = 0; j < 8; j++) {
        int c = c0 + j;
        af[j] = fmaf(x0, Wp[c], fmaf(x1, Wp[H_+c], bp[c]));
    }
    #pragma unroll
    for (int k = 0; k < NT_; k++) {
        #pragma unroll
        for (int j = 0; j < 8; j++)
            af[j] = fmaf(te[k], Wp[(2+k)*H_+c0+j], af[j]);
    }
    unsigned short of[8];
    #pragma unroll
    for (int j = 0; j < 8; j++) of[j] = f2b(af[j]);
    *(uint4*)&inp[row*H_ + c0] = *(const uint4*)of;
}

// ---------------------------------------------------------------------------
// K3g: PURE GEMM. AT[row][0..511] = inp@Wz (raw), AT[row][512..1023] = inp@Wh.
// 128x128 tile, BK=32, 80B-pad LDS, register prefetch, XCD remap.
// ---------------------------------------------------------------------------
__global__ __launch_bounds__(256) void k3g(
    const unsigned short* __restrict__ inp,   // [M][512] bf16
    const unsigned short* __restrict__ WT,    // [1024][512] bf16 (Wz rows, Wh rows)
    unsigned short* __restrict__ zt_out,      // [M][NWS_] bf16
    int nwg)
{
    __shared__ __align__(16) unsigned short As[128*40];
    __shared__ __align__(16) unsigned short Bs[128*40];
    int tid = threadIdx.x;
    int lane = tid & 63, w = tid >> 6;
    int wm = w >> 1, wn = w & 1;
    int kg = lane >> 4, lr = lane & 15;

    int bid = blockIdx.x;
    int cpx = nwg >> 3;
    int tile = (bid & 7) * cpx + (bid >> 3);
    int row0 = (tile >> 3) * 128;
    int n0   = (tile & 7) * 128;

    f32x4 acc[4][4];
    #pragma unroll
    for (int m = 0; m < 4; m++)
        #pragma unroll
        for (int n = 0; n < 4; n++) acc[m][n] = (f32x4){0.f,0.f,0.f,0.f};

    int ar = tid >> 1, aseg = tid & 1;

    uint4 va0, va1, vb0, vb1;
    {
        const uint4* ga = (const uint4*)&inp[(size_t)(row0+ar)*H_ + aseg*16];
        va0 = ga[0]; va1 = ga[1];
        const uint4* gb = (const uint4*)&WT[(size_t)(n0+ar)*H_ + aseg*16];
        vb0 = gb[0]; vb1 = gb[1];
    }

    for (int k0 = 0; k0 < H_; k0 += 32) {
        __syncthreads();
        *(uint4*)&As[ar*40 + aseg*16]     = va0;
        *(uint4*)&As[ar*40 + aseg*16 + 8] = va1;
        *(uint4*)&Bs[ar*40 + aseg*16]     = vb0;
        *(uint4*)&Bs[ar*40 + aseg*16 + 8] = vb1;
        __syncthreads();
        if (k0 + 32 < H_) {
            const uint4* ga = (const uint4*)&inp[(size_t)(row0+ar)*H_ + k0+32 + aseg*16];
            va0 = ga[0]; va1 = ga[1];
            const uint4* gb = (const uint4*)&WT[(size_t)(n0+ar)*H_ + k0+32 + aseg*16];
            vb0 = gb[0]; vb1 = gb[1];
        }
        bf16x8 af[4], bf[4];
        #pragma unroll
        for (int m = 0; m < 4; m++)
            af[m] = *(const bf16x8*)&As[(wm*64 + m*16 + lr)*40 + kg*8];
        #pragma unroll
        for (int n = 0; n < 4; n++)
            bf[n] = *(const bf16x8*)&Bs[(wn*64 + n*16 + lr)*40 + kg*8];
        #pragma unroll
        for (int m = 0; m < 4; m++)
            #pragma unroll
            for (int n = 0; n < 4; n++)
                acc[m][n] = __builtin_amdgcn_mfma_f32_16x16x32_bf16(af[m], bf[n], acc[m][n], 0, 0, 0);
    }

    #pragma unroll
    for (int m = 0; m < 4; m++)
        #pragma unroll
        for (int n = 0; n < 4; n++) {
            int colg = n0 + wn*64 + n*16 + lr;
            #pragma unroll
            for (int r = 0; r < 4; r++) {
                int rowg = row0 + wm*64 + m*16 + kg*4 + r;
                zt_out[(size_t)rowg*NWS_ + colg] = f2b(acc[m][n][r]);
            }
        }
}

// ---------------------------------------------------------------------------
// K4a: bias + activations + chunked scan pass A, in place on AT rows.
// ---------------------------------------------------------------------------
__global__ __launch_bounds__(256) void k4a(
    unsigned short* __restrict__ ATF, unsigned short* __restrict__ ATB,
    const float* __restrict__ bzf, const float* __restrict__ bhf,
    const float* __restrict__ bzb, const float* __restrict__ bhb,
    float* __restrict__ Scar, float* __restrict__ Pcar, int nb)
{
    int g = blockIdx.x*256 + threadIdx.x;
    int col   = g & (H_-1);
    int chunk = (g >> 9) & (CH_-1);
    int rest  = g >> 13;
    int bb    = rest % nb;
    int dir   = rest / nb;
    unsigned short* AT = dir ? ATB : ATF;
    float bzv = (dir ? bzb : bzf)[col];
    float bhv = (dir ? bhb : bhf)[col];
    size_t base = (size_t)bb * L_ * NWS_ + col;
    float h = 0.f, pp = 1.f;
    if (dir == 0) {
        int lo = chunk * CL_;
        for (int p = 0; p < CL_; p += 8) {
            unsigned short zv[8], hv[8];
            #pragma unroll
            for (int j = 0; j < 8; j++) {
                size_t idx = base + (size_t)(lo+p+j)*NWS_;
                zv[j] = AT[idx]; hv[j] = AT[idx + H_];
            }
            #pragma unroll
            for (int j = 0; j < 8; j++) {
                size_t idx = base + (size_t)(lo+p+j)*NWS_;
                float zg = sigmoid_f(b2f(zv[j]) + bzv);
                float a  = 1.f - zg;
                float bg = zg * tanh_f(b2f(hv[j]) + bhv);
                AT[idx]      = f2b(h);
                AT[idx + H_] = f2b(pp);
                h = fmaf(a, h, bg);
                pp *= a;
            }
        }
    } else {
        int hi = chunk * CL_ + CL_ - 1;
        for (int p = 0; p < CL_; p += 8) {
            unsigned short zv[8], hv[8];
            #pragma unroll
            for (int j = 0; j < 8; j++) {
                size_t idx = base + (size_t)(hi-p-j)*NWS_;
                zv[j] = AT[idx]; hv[j] = AT[idx + H_];
            }
            #pragma unroll
            for (int j = 0; j < 8; j++) {
                size_t idx = base + (size_t)(hi-p-j)*NWS_;
                float zg = sigmoid_f(b2f(zv[j]) + bzv);
                float a  = 1.f - zg;
                float bg = zg * tanh_f(b2f(hv[j]) + bhv);
                AT[idx]      = f2b(h);
                AT[idx + H_] = f2b(pp);
                h = fmaf(a, h, bg);
                pp *= a;
            }
        }
    }
    int ci = ((dir*nb + bb)*CH_ + chunk)*H_ + col;
    Scar[ci] = h; Pcar[ci] = pp;
}

// K4b: chain carries across chunks.
__global__ __launch_bounds__(256) void k4b(
    const float* __restrict__ Scar, const float* __restrict__ Pcar,
    float* __restrict__ Hstart, int nb)
{
    int g = blockIdx.x*256 + threadIdx.x;
    int col  = g & (H_-1);
    int rest = g >> 9;
    int bb   = rest % nb;
    int dir  = rest / nb;
    int baseci = (dir*nb + bb)*CH_;
    float h = 0.f;
    if (dir == 0) {
        for (int c = 0; c < CH_; c++) {
            int ci = (baseci + c)*H_ + col;
            Hstart[ci] = h;
            h = Scar[ci] + Pcar[ci]*h;
        }
    } else {
        for (int c = CH_-1; c >= 0; c--) {
            int ci = (baseci + c)*H_ + col;
            Hstart[ci] = h;
            h = Scar[ci] + Pcar[ci]*h;
        }
    }
}

// ---------------------------------------------------------------------------
// K5 fused v5: LN->LDS-A (no hbi materialization, WRITE~0) + head GEMM with
// cooperative double-buffered LDS staging of packed-P per K-step-64.
// 32 rows, 4 waves (2m x 2n), 135 KB LDS, 1 block/CU by design — latency
// hidden by structure (coalesced 32KB B-bursts issued one MFMA-phase ahead).
// ---------------------------------------------------------------------------
__global__ __launch_bounds__(256, 1) void k5_fused(
    const unsigned short* __restrict__ ATF, const unsigned short* __restrict__ ATB,
    const float* __restrict__ Hstart,
    const float* __restrict__ tenc,
    const float* __restrict__ ln_g, const float* __restrict__ ln_b,
    const float* __restrict__ tsp,
    const uint4* __restrict__ P,              // [34*1024] packed fragments
    const float* __restrict__ bg1, const float* __restrict__ Wg2,
    const float* __restrict__ bg2,
    float* __restrict__ out, int nb)
{
    __shared__ __align__(16) unsigned short A[RB5_*ASTR_];   // 68 KB
    __shared__ __align__(16) uint4 Bs[2][2048];              // 64 KB
    __shared__ float red[2][RB5_];
    int tid = threadIdx.x, lane = tid & 63, wv = tid >> 6;
    int kg = lane >> 4, lr = lane & 15;
    int wm = wv >> 1, wn = wv & 1;
    int row0 = blockIdx.x * RB5_;
    float ts = tsp[0];

    // ---- issue step-0 B staging loads immediately (fly during LN) ----
    uint4 rB[8];
    #pragma unroll
    for (int j = 0; j < 8; j++) rB[j] = P[j*256 + tid];

    // ---- LN phase: wave wv handles rows wv*8 .. wv*8+7 ----
    int bb    = row0 >> 11;          // / L_
    int chunk = (row0 & (L_-1)) >> 7;
    int cif = (bb*CH_ + chunk)*H_;
    int cib = ((nb + bb)*CH_ + chunk)*H_;
    int c0 = lane*8;
    float4 hfa = *(const float4*)&Hstart[cif + c0];
    float4 hfb = *(const float4*)&Hstart[cif + c0 + 4];
    float4 hba = *(const float4*)&Hstart[cib + c0];
    float4 hbb = *(const float4*)&Hstart[cib + c0 + 4];
    float h0f[8] = {hfa.x,hfa.y,hfa.z,hfa.w,hfb.x,hfb.y,hfb.z,hfb.w};
    float h0b[8] = {hba.x,hba.y,hba.z,hba.w,hbb.x,hbb.y,hbb.z,hbb.w};

    float gf[8], bf_[8], gb_[8], bb_[8];
    #pragma unroll
    for (int j = 0; j < 8; j++) {
        gf[j]  = ln_g[c0+j];     bf_[j] = ln_b[c0+j];
        gb_[j] = ln_g[H_+c0+j];  bb_[j] = ln_b[H_+c0+j];
    }
    float gt = 0.f, bt = 0.f;
    if (lane < NT_) { gt = ln_g[2*H_+lane]; bt = ln_b[2*H_+lane]; }

    #pragma unroll
    for (int i = 0; i < 8; i++) {
        int r = wv*8 + i;
        size_t row = (size_t)row0 + r;
        size_t rb = row * NWS_;
        uint4 SF = *(const uint4*)&ATF[rb + c0];
        uint4 PF = *(const uint4*)&ATF[rb + H_ + c0];
        uint4 SB = *(const uint4*)&ATB[rb + c0];
        uint4 PB = *(const uint4*)&ATB[rb + H_ + c0];
        const unsigned short* sf = (const unsigned short*)&SF;
        const unsigned short* pf = (const unsigned short*)&PF;
        const unsigned short* sb = (const unsigned short*)&SB;
        const unsigned short* pb = (const unsigned short*)&PB;
        float fv[8], bv[8];
        float S = 0.f, Q = 0.f;
        #pragma unroll
        for (int j = 0; j < 8; j++) {
            fv[j] = fmaf(b2f(pf[j]), h0f[j], b2f(sf[j]));
            S += fv[j]; Q += fv[j]*fv[j];
            bv[j] = fmaf(b2f(pb[j]), h0b[j], b2f(sb[j]));
            S += bv[j]; Q += bv[j]*bv[j];
        }
        float tv = 0.f;
        if (lane < NT_) { tv = tenc[row*NT_ + lane]; S += tv; Q += tv*tv; }
        #pragma unroll
        for (int off = 32; off > 0; off >>= 1) {
            S += __shfl_xor(S, off, 64);
            Q += __shfl_xor(Q, off, 64);
        }
        float mu = S * (1.f/1032.f);
        float rs = rsqrtf(Q * (1.f/1032.f) - mu*mu + 1e-5f);
        int key = r & 7;
        unsigned short o[8];
        #pragma unroll
        for (int j = 0; j < 8; j++) o[j] = f2b((fv[j]-mu)*rs*gf[j] + bf_[j]);
        *(uint4*)&A[r*ASTR_ + ((lane ^ key)*8)] = *(const uint4*)o;
        #pragma unroll
        for (int j = 0; j < 8; j++) o[j] = f2b((bv[j]-mu)*rs*gb_[j] + bb_[j]);
        *(uint4*)&A[r*ASTR_ + (((64+lane) ^ key)*8)] = *(const uint4*)o;
        if (lane < NT_) {
            // chunk 128: cols 1024..1031 (tenc part)
            A[r*ASTR_ + ((128 ^ key)*8) + lane] =
                f2b(((tv-mu)*rs*gt + bt) * ts);
        } else {
            // chunks 129..135: cols 1032..1087 zero (lane 8..63)
            int cc = 128 + (lane >> 3);
            A[r*ASTR_ + ((cc ^ key)*8) + (lane & 7)] = 0;
        }
    }
    __syncthreads();                         // A complete

    // store step-0 B, issue step-1 loads
    #pragma unroll
    for (int j = 0; j < 8; j++) Bs[0][j*256 + tid] = rB[j];
    #pragma unroll
    for (int j = 0; j < 8; j++) rB[j] = P[2048 + j*256 + tid];
    __syncthreads();                         // Bs[0] visible

    // ---- GEMM: 17 steps of K=64, B double-buffered, loads 1 step ahead ----
    f32x4 acc[8];
    #pragma unroll
    for (int n = 0; n < 8; n++) acc[n] = (f32x4){0.f,0.f,0.f,0.f};

    int keyA = lr & 7;
    int arow0 = (wm*16 + lr)*ASTR_;
    int bcol4 = (wn*128)*4 + lr*4 + kg;      // uint4 index base within kb-block

    for (int s = 0; s < 17; s++) {
        const uint4* Bc = Bs[s & 1];
        #pragma unroll
        for (int kk = 0; kk < 2; kk++) {
            int ch = s*8 + kk*4 + kg;
            bf16x8 af = *(const bf16x8*)&A[arow0 + ((ch ^ keyA)*8)];
            #pragma unroll
            for (int n = 0; n < 8; n++) {
                bf16x8 bf = *(const bf16x8*)&Bc[kk*1024 + bcol4 + n*64];
                acc[n] = __builtin_amdgcn_mfma_f32_16x16x32_bf16(af, bf, acc[n], 0, 0, 0);
            }
        }
        if (s < 16) {
            __syncthreads();                 // everyone done reading Bs[(s+1)&1]
            #pragma unroll
            for (int j = 0; j < 8; j++) Bs[(s+1) & 1][j*256 + tid] = rB[j];
            if (s < 15) {
                const uint4* ps = P + (s+2)*2048 + tid;
                #pragma unroll
                for (int j = 0; j < 8; j++) rB[j] = ps[j*256];
            }
            __syncthreads();                 // new buffer visible
        }
    }

    // ---- epilogue: gelu + *Wg2, reduce over this wave's 128 cols ----
    float rsum[4] = {0.f,0.f,0.f,0.f};
    #pragma unroll
    for (int n = 0; n < 8; n++) {
        int colg = wn*128 + n*16 + lr;
        float bgv = bg1[colg], w2v = Wg2[colg];
        #pragma unroll
        for (int r = 0; r < 4; r++) {
            float gv = gelu_f(acc[n][r] + bgv);
            rsum[r] = fmaf(gv, w2v, rsum[r]);
        }
    }
    #pragma unroll
    for (int off = 1; off < 16; off <<= 1)
        #pragma unroll
        for (int r = 0; r < 4; r++)
            rsum[r] += __shfl_xor(rsum[r], off, 64);
    if (lr == 0) {
        #pragma unroll
        for (int r = 0; r < 4; r++)
            red[wn][wm*16 + kg*4 + r] = rsum[r];
    }
    __syncthreads();
    if (tid < RB5_)
        out[row0 + tid] = red[0][tid] + red[1][tid] + bg2[0];
}

// ---------------------------------------------------------------------------
extern "C" void kernel_launch(void* const* d_in, const int* in_sizes, int n_in,
                              void* d_out, int out_size, void* d_ws, size_t ws_size,
                              hipStream_t stream)
{
    const float* x    = (const float*)d_in[0];
    const float* t    = (const float*)d_in[1];
    const float* Wt1  = (const float*)d_in[2];
    const float* bt1  = (const float*)d_in[3];
    const float* Wt2  = (const float*)d_in[4];
    const float* bt2  = (const float*)d_in[5];
    const float* Wpf  = (const float*)d_in[6];
    const float* bpf  = (const float*)d_in[7];
    const float* Wpb  = (const float*)d_in[8];
    const float* bpb  = (const float*)d_in[9];
    const float* Wzf  = (const float*)d_in[10];
    const float* bzf  = (const float*)d_in[11];
    const float* Whf  = (const float*)d_in[12];
    const float* bhf  = (const float*)d_in[13];
    const float* Wzb  = (const float*)d_in[14];
    const float* bzb  = (const float*)d_in[15];
    const float* Whb  = (const float*)d_in[16];
    const float* bhb  = (const float*)d_in[17];
    const float* ln_g = (const float*)d_in[18];
    const float* ln_b = (const float*)d_in[19];
    const float* tsc  = (const float*)d_in[20];
    const float* Wg1  = (const float*)d_in[21];
    const float* bg1  = (const float*)d_in[22];
    const float* Wg2  = (const float*)d_in[23];
    const float* bg2  = (const float*)d_in[24];
    float* out = (float*)d_out;

    char* p = (char*)d_ws;
    auto carve = [&](size_t bytes) -> char* {
        char* q = p; p += (bytes + 255) & ~(size_t)255; return q;
    };

    unsigned short* WTf = (unsigned short*)carve((size_t)2*H_*H_*2);
    unsigned short* WTb = (unsigned short*)carve((size_t)2*H_*H_*2);
    uint4*          Pg  = (uint4*)carve((size_t)34*1024*16);

    const size_t perBatch = (size_t)L_*H_*2            // inp
                          + (size_t)L_*NWS_*2*2        // ATF + ATB
                          + (size_t)L_*NT_*4           // tenc
                          + (size_t)CH_*H_*4*3*2;      // carries
    size_t fixedUsed = (size_t)(p - (char*)d_ws) + 64*1024;
    int NB = B_;
    while (NB > 1 && fixedUsed + (size_t)NB*perBatch > ws_size) NB >>= 1;

    unsigned short* inp = (unsigned short*)carve((size_t)NB*L_*H_*2);
    unsigned short* ATF = (unsigned short*)carve((size_t)NB*L_*NWS_*2);
    unsigned short* ATB = (unsigned short*)carve((size_t)NB*L_*NWS_*2);
    float* tenc   = (float*)carve((size_t)NB*L_*NT_*4);
    float* Scar   = (float*)carve((size_t)2*NB*CH_*H_*4);
    float* Pcar   = (float*)carve((size_t)2*NB*CH_*H_*4);
    float* Hstart = (float*)carve((size_t)2*NB*CH_*H_*4);

    {
        dim3 g(H_/32, H_/32);
        kT<<<g, 256, 0, stream>>>(Wzf, WTf,         H_, H_, H_);
        kT<<<g, 256, 0, stream>>>(Whf, WTf + H_*H_, H_, H_, H_);
        kT<<<g, 256, 0, stream>>>(Wzb, WTb,         H_, H_, H_);
        kT<<<g, 256, 0, stream>>>(Whb, WTb + H_*H_, H_, H_, H_);
        kP<<<136, 256, 0, stream>>>(Wg1, Pg);
    }

    for (int b0 = 0; b0 < B_; b0 += NB) {
        int rows = NB * L_;
        int nwg3 = (rows/128) * 8;

        k1_tenc_inp<<<rows/4, 256, 0, stream>>>(
            x + (size_t)b0*L_*2, t + (size_t)b0*L_,
            Wt1, bt1, Wt2, bt2, Wpf, bpf, tenc, inp);
        k3g<<<nwg3, 256, 0, stream>>>(inp, WTf, ATF, nwg3);

        k1_tenc_inp<<<rows/4, 256, 0, stream>>>(
            x + (size_t)b0*L_*2, t + (size_t)b0*L_,
            Wt1, bt1, Wt2, bt2, Wpb, bpb, tenc, inp);
        k3g<<<nwg3, 256, 0, stream>>>(inp, WTb, ATB, nwg3);

        int scanThreads = 2*NB*H_*CH_;
        k4a<<<scanThreads/256, 256, 0, stream>>>(ATF, ATB, bzf, bhf, bzb, bhb,
                                                 Scar, Pcar, NB);
        k4b<<<(2*NB*H_)/256, 256, 0, stream>>>(Scar, Pcar, Hstart, NB);

        k5_fused<<<rows/RB5_, 256, 0, stream>>>(
            ATF, ATB, Hstart, tenc, ln_g, ln_b, tsc,
            Pg, bg1, Wg2, bg2, out + (size_t)b0*L_, NB);
    }
}

// Round 12
// 407.493 us; speedup vs baseline: 1.0543x; 1.0543x over previous
//
#include <hip/hip_runtime.h>
#include <hip/hip_bf16.h>
#include <math.h>

#define B_    16
#define L_    2048
#define H_    512
#define NT_   8
#define OUT_  1032
#define HEAD_ 256
#define CH_   16
#define CL_   (L_/CH_)   // 128
#define NWS_  1152       // AT row stride in shorts (z|h -> S|PP -> hbi in place)

typedef short bf16x8 __attribute__((ext_vector_type(8)));
typedef float f32x4  __attribute__((ext_vector_type(4)));

__device__ __forceinline__ float b2f(unsigned short u) {
    union { unsigned int u32; float f; } v; v.u32 = ((unsigned int)u) << 16; return v.f;
}
__device__ __forceinline__ unsigned short f2b(float f) {
    __hip_bfloat16 h = __float2bfloat16(f);
    return *reinterpret_cast<unsigned short*>(&h);
}
__device__ __forceinline__ float sigmoid_f(float x) {
    return 1.f / (1.f + exp2f(-1.44269504f * x));
}
__device__ __forceinline__ float tanh_f(float x) {
    float e = exp2f(2.88539008f * x);
    return 1.f - 2.f / (e + 1.f);
}
__device__ __forceinline__ float gelu_f(float g) {
    float u  = 0.70710678118654752f * g;
    float ax = fabsf(u);
    float t  = 1.f / (1.f + 0.3275911f * ax);
    float poly = ((((1.061405429f*t - 1.453152027f)*t + 1.421413741f)*t
                   - 0.284496736f)*t + 0.254829592f)*t;
    float e  = exp2f(-1.44269504f * ax * ax);
    float er = 1.f - poly * e;
    er = (u < 0.f) ? -er : er;
    return 0.5f * g * (1.f + er);
}

// ---------------------------------------------------------------------------
// kT: transpose + f32->bf16. in f32 [R][C] -> out bf16 [C][RP], zero r>=R.
// ---------------------------------------------------------------------------
__global__ __launch_bounds__(256) void kT(const float* __restrict__ in,
                                          unsigned short* __restrict__ out,
                                          int R, int C, int RP)
{
    __shared__ float tile[32][33];
    int c0 = blockIdx.x * 32, r0 = blockIdx.y * 32;
    int tx = threadIdx.x & 31, ty = threadIdx.x >> 5;
    #pragma unroll
    for (int j = 0; j < 32; j += 8) {
        int r = r0 + ty + j, c = c0 + tx;
        tile[ty + j][tx] = (r < R && c < C) ? in[(size_t)r*C + c] : 0.f;
    }
    __syncthreads();
    #pragma unroll
    for (int j = 0; j < 32; j += 8) {
        int c = c0 + ty + j, r = r0 + tx;
        if (c < C && r < RP) out[(size_t)c*RP + r] = f2b(tile[tx][ty + j]);
    }
}

// ---------------------------------------------------------------------------
// kP2: pack Wg1 (f32 [OUT_][256]) into LANE-ORDERED fragment layout:
// P2[s*2048 + (kk*16+cg)*64 + kg*16 + lr] = bf16x8 of
//   Wg1[k = s*64+kk*32+kg*8 .. +8][col = cg*16+lr]   (zero k>=OUT_)
// Global load, LDS store, and LDS frag-read in k5b are then all linear.
// ---------------------------------------------------------------------------
__global__ __launch_bounds__(256) void kP2(const float* __restrict__ Wg1,
                                           uint4* __restrict__ P2)
{
    int idx = blockIdx.x*256 + threadIdx.x;
    if (idx >= 17*2048) return;
    int s  = idx >> 11;
    int u  = idx & 2047;
    int q  = u >> 6;          // kk*16 + cg
    int kk = q >> 4, cg = q & 15;
    int r6 = u & 63;
    int kg = r6 >> 4, lr = r6 & 15;
    int k0  = s*64 + kk*32 + kg*8;
    int col = cg*16 + lr;
    unsigned short o[8];
    #pragma unroll
    for (int j = 0; j < 8; j++) {
        int k = k0 + j;
        o[j] = (k < OUT_) ? f2b(Wg1[(size_t)k*HEAD_ + col]) : (unsigned short)0;
    }
    P2[idx] = *(const uint4*)o;
}

// ---------------------------------------------------------------------------
// K1 (per-dir): t_enc MLP + inp = xc @ Wp + bp. wave-per-row.
// ---------------------------------------------------------------------------
__global__ __launch_bounds__(256) void k1_tenc_inp(
    const float* __restrict__ x, const float* __restrict__ t,
    const float* __restrict__ Wt1, const float* __restrict__ bt1,
    const float* __restrict__ Wt2, const float* __restrict__ bt2,
    const float* __restrict__ Wp, const float* __restrict__ bp,
    float* __restrict__ t_enc,
    unsigned short* __restrict__ inp)
{
    int wv = threadIdx.x >> 6, lane = threadIdx.x & 63;
    size_t row = (size_t)blockIdx.x*4 + wv;
    float tv = t[row];
    float r1[NT_], te[NT_];
    #pragma unroll
    for (int k = 0; k < NT_; k++) r1[k] = fmaxf(tv*Wt1[k] + bt1[k], 0.f);
    #pragma unroll
    for (int j = 0; j < NT_; j++) {
        float a = bt2[j];
        #pragma unroll
        for (int k = 0; k < NT_; k++) a = fmaf(r1[k], Wt2[k*NT_+j], a);
        te[j] = a;
    }
    if (lane < NT_) t_enc[row*NT_ + lane] = te[lane];
    float x0 = x[row*2+0], x1 = x[row*2+1];
    int c0 = lane*8;
    float af[8];
    #pragma unroll
    for (int j = 0; j < 8; j++) {
        int c = c0 + j;
        af[j] = fmaf(x0, Wp[c], fmaf(x1, Wp[H_+c], bp[c]));
    }
    #pragma unroll
    for (int k = 0; k < NT_; k++) {
        #pragma unroll
        for (int j = 0; j < 8; j++)
            af[j] = fmaf(te[k], Wp[(2+k)*H_+c0+j], af[j]);
    }
    unsigned short of[8];
    #pragma unroll
    for (int j = 0; j < 8; j++) of[j] = f2b(af[j]);
    *(uint4*)&inp[row*H_ + c0] = *(const uint4*)of;
}

// ---------------------------------------------------------------------------
// K3g: PURE GEMM. AT[row][0..511] = inp@Wz (raw), AT[row][512..1023] = inp@Wh.
// 128x128 tile, BK=32, 80B-pad LDS, register prefetch, XCD remap.
// ---------------------------------------------------------------------------
__global__ __launch_bounds__(256) void k3g(
    const unsigned short* __restrict__ inp,   // [M][512] bf16
    const unsigned short* __restrict__ WT,    // [1024][512] bf16 (Wz rows, Wh rows)
    unsigned short* __restrict__ zt_out,      // [M][NWS_] bf16
    int nwg)
{
    __shared__ __align__(16) unsigned short As[128*40];
    __shared__ __align__(16) unsigned short Bs[128*40];
    int tid = threadIdx.x;
    int lane = tid & 63, w = tid >> 6;
    int wm = w >> 1, wn = w & 1;
    int kg = lane >> 4, lr = lane & 15;

    int bid = blockIdx.x;
    int cpx = nwg >> 3;
    int tile = (bid & 7) * cpx + (bid >> 3);
    int row0 = (tile >> 3) * 128;
    int n0   = (tile & 7) * 128;

    f32x4 acc[4][4];
    #pragma unroll
    for (int m = 0; m < 4; m++)
        #pragma unroll
        for (int n = 0; n < 4; n++) acc[m][n] = (f32x4){0.f,0.f,0.f,0.f};

    int ar = tid >> 1, aseg = tid & 1;

    uint4 va0, va1, vb0, vb1;
    {
        const uint4* ga = (const uint4*)&inp[(size_t)(row0+ar)*H_ + aseg*16];
        va0 = ga[0]; va1 = ga[1];
        const uint4* gb = (const uint4*)&WT[(size_t)(n0+ar)*H_ + aseg*16];
        vb0 = gb[0]; vb1 = gb[1];
    }

    for (int k0 = 0; k0 < H_; k0 += 32) {
        __syncthreads();
        *(uint4*)&As[ar*40 + aseg*16]     = va0;
        *(uint4*)&As[ar*40 + aseg*16 + 8] = va1;
        *(uint4*)&Bs[ar*40 + aseg*16]     = vb0;
        *(uint4*)&Bs[ar*40 + aseg*16 + 8] = vb1;
        __syncthreads();
        if (k0 + 32 < H_) {
            const uint4* ga = (const uint4*)&inp[(size_t)(row0+ar)*H_ + k0+32 + aseg*16];
            va0 = ga[0]; va1 = ga[1];
            const uint4* gb = (const uint4*)&WT[(size_t)(n0+ar)*H_ + k0+32 + aseg*16];
            vb0 = gb[0]; vb1 = gb[1];
        }
        bf16x8 af[4], bf[4];
        #pragma unroll
        for (int m = 0; m < 4; m++)
            af[m] = *(const bf16x8*)&As[(wm*64 + m*16 + lr)*40 + kg*8];
        #pragma unroll
        for (int n = 0; n < 4; n++)
            bf[n] = *(const bf16x8*)&Bs[(wn*64 + n*16 + lr)*40 + kg*8];
        #pragma unroll
        for (int m = 0; m < 4; m++)
            #pragma unroll
            for (int n = 0; n < 4; n++)
                acc[m][n] = __builtin_amdgcn_mfma_f32_16x16x32_bf16(af[m], bf[n], acc[m][n], 0, 0, 0);
    }

    #pragma unroll
    for (int m = 0; m < 4; m++)
        #pragma unroll
        for (int n = 0; n < 4; n++) {
            int colg = n0 + wn*64 + n*16 + lr;
            #pragma unroll
            for (int r = 0; r < 4; r++) {
                int rowg = row0 + wm*64 + m*16 + kg*4 + r;
                zt_out[(size_t)rowg*NWS_ + colg] = f2b(acc[m][n][r]);
            }
        }
}

// ---------------------------------------------------------------------------
// K4a: bias + activations + chunked scan pass A, in place on AT rows.
// ---------------------------------------------------------------------------
__global__ __launch_bounds__(256) void k4a(
    unsigned short* __restrict__ ATF, unsigned short* __restrict__ ATB,
    const float* __restrict__ bzf, const float* __restrict__ bhf,
    const float* __restrict__ bzb, const float* __restrict__ bhb,
    float* __restrict__ Scar, float* __restrict__ Pcar, int nb)
{
    int g = blockIdx.x*256 + threadIdx.x;
    int col   = g & (H_-1);
    int chunk = (g >> 9) & (CH_-1);
    int rest  = g >> 13;
    int bb    = rest % nb;
    int dir   = rest / nb;
    unsigned short* AT = dir ? ATB : ATF;
    float bzv = (dir ? bzb : bzf)[col];
    float bhv = (dir ? bhb : bhf)[col];
    size_t base = (size_t)bb * L_ * NWS_ + col;
    float h = 0.f, pp = 1.f;
    if (dir == 0) {
        int lo = chunk * CL_;
        for (int p = 0; p < CL_; p += 8) {
            unsigned short zv[8], hv[8];
            #pragma unroll
            for (int j = 0; j < 8; j++) {
                size_t idx = base + (size_t)(lo+p+j)*NWS_;
                zv[j] = AT[idx]; hv[j] = AT[idx + H_];
            }
            #pragma unroll
            for (int j = 0; j < 8; j++) {
                size_t idx = base + (size_t)(lo+p+j)*NWS_;
                float zg = sigmoid_f(b2f(zv[j]) + bzv);
                float a  = 1.f - zg;
                float bg = zg * tanh_f(b2f(hv[j]) + bhv);
                AT[idx]      = f2b(h);
                AT[idx + H_] = f2b(pp);
                h = fmaf(a, h, bg);
                pp *= a;
            }
        }
    } else {
        int hi = chunk * CL_ + CL_ - 1;
        for (int p = 0; p < CL_; p += 8) {
            unsigned short zv[8], hv[8];
            #pragma unroll
            for (int j = 0; j < 8; j++) {
                size_t idx = base + (size_t)(hi-p-j)*NWS_;
                zv[j] = AT[idx]; hv[j] = AT[idx + H_];
            }
            #pragma unroll
            for (int j = 0; j < 8; j++) {
                size_t idx = base + (size_t)(hi-p-j)*NWS_;
                float zg = sigmoid_f(b2f(zv[j]) + bzv);
                float a  = 1.f - zg;
                float bg = zg * tanh_f(b2f(hv[j]) + bhv);
                AT[idx]      = f2b(h);
                AT[idx + H_] = f2b(pp);
                h = fmaf(a, h, bg);
                pp *= a;
            }
        }
    }
    int ci = ((dir*nb + bb)*CH_ + chunk)*H_ + col;
    Scar[ci] = h; Pcar[ci] = pp;
}

// K4b: chain carries across chunks.
__global__ __launch_bounds__(256) void k4b(
    const float* __restrict__ Scar, const float* __restrict__ Pcar,
    float* __restrict__ Hstart, int nb)
{
    int g = blockIdx.x*256 + threadIdx.x;
    int col  = g & (H_-1);
    int rest = g >> 9;
    int bb   = rest % nb;
    int dir  = rest / nb;
    int baseci = (dir*nb + bb)*CH_;
    float h = 0.f;
    if (dir == 0) {
        for (int c = 0; c < CH_; c++) {
            int ci = (baseci + c)*H_ + col;
            Hstart[ci] = h;
            h = Scar[ci] + Pcar[ci]*h;
        }
    } else {
        for (int c = CH_-1; c >= 0; c--) {
            int ci = (baseci + c)*H_ + col;
            Hstart[ci] = h;
            h = Scar[ci] + Pcar[ci]*h;
        }
    }
}

// ---------------------------------------------------------------------------
// K5a: streaming LN. h = S + PP*h0 (both dirs), LN(1032), affine + ts.
// Writes hbi bf16 IN-PLACE into the ATF row slot (cols 0..1087, rest pad).
// Wave-per-row (read-before-write within the owning wave -> safe).
// ---------------------------------------------------------------------------
__global__ __launch_bounds__(256) void k5a_ln(
    unsigned short* __restrict__ ATF, const unsigned short* __restrict__ ATB,
    const float* __restrict__ Hstart, const float* __restrict__ tenc,
    const float* __restrict__ ln_g, const float* __restrict__ ln_b,
    const float* __restrict__ tsp, int nb)
{
    int wv = threadIdx.x >> 6, lane = threadIdx.x & 63;
    size_t row = (size_t)blockIdx.x*4 + wv;
    int bb    = (int)(row >> 11);
    int chunk = ((int)row & (L_-1)) >> 7;
    int cif = (bb*CH_ + chunk)*H_;
    int cib = ((nb + bb)*CH_ + chunk)*H_;
    int c0 = lane*8;
    float ts = tsp[0];

    size_t rb = row * NWS_;
    uint4 SF = *(const uint4*)&ATF[rb + c0];
    uint4 PF = *(const uint4*)&ATF[rb + H_ + c0];
    uint4 SB = *(const uint4*)&ATB[rb + c0];
    uint4 PB = *(const uint4*)&ATB[rb + H_ + c0];
    float4 hfa = *(const float4*)&Hstart[cif + c0];
    float4 hfb = *(const float4*)&Hstart[cif + c0 + 4];
    float4 hba = *(const float4*)&Hstart[cib + c0];
    float4 hbb = *(const float4*)&Hstart[cib + c0 + 4];
    float h0f[8] = {hfa.x,hfa.y,hfa.z,hfa.w,hfb.x,hfb.y,hfb.z,hfb.w};
    float h0b[8] = {hba.x,hba.y,hba.z,hba.w,hbb.x,hbb.y,hbb.z,hbb.w};
    const unsigned short* sf = (const unsigned short*)&SF;
    const unsigned short* pf = (const unsigned short*)&PF;
    const unsigned short* sb = (const unsigned short*)&SB;
    const unsigned short* pb = (const unsigned short*)&PB;

    float fv[8], bv[8];
    float S = 0.f, Q = 0.f;
    #pragma unroll
    for (int j = 0; j < 8; j++) {
        fv[j] = fmaf(b2f(pf[j]), h0f[j], b2f(sf[j]));
        S += fv[j]; Q += fv[j]*fv[j];
        bv[j] = fmaf(b2f(pb[j]), h0b[j], b2f(sb[j]));
        S += bv[j]; Q += bv[j]*bv[j];
    }
    float tv = 0.f;
    if (lane < NT_) { tv = tenc[row*NT_ + lane]; S += tv; Q += tv*tv; }
    #pragma unroll
    for (int off = 32; off > 0; off >>= 1) {
        S += __shfl_xor(S, off, 64);
        Q += __shfl_xor(Q, off, 64);
    }
    float mu = S * (1.f/1032.f);
    float rs = rsqrtf(Q * (1.f/1032.f) - mu*mu + 1e-5f);

    unsigned short o[8];
    #pragma unroll
    for (int j = 0; j < 8; j++)
        o[j] = f2b((fv[j]-mu)*rs*ln_g[c0+j] + ln_b[c0+j]);
    *(uint4*)&ATF[rb + c0] = *(const uint4*)o;
    #pragma unroll
    for (int j = 0; j < 8; j++)
        o[j] = f2b((bv[j]-mu)*rs*ln_g[H_+c0+j] + ln_b[H_+c0+j]);
    *(uint4*)&ATF[rb + H_ + c0] = *(const uint4*)o;
    if (lane < NT_) {
        int c = 2*H_ + lane;
        ATF[rb + 1024 + lane] = f2b(((tv-mu)*rs*ln_g[c] + ln_b[c]) * ts);
    } else {
        ATF[rb + 1024 + lane] = 0;   // lanes 8..63 zero cols 1032..1087
    }
}

// ---------------------------------------------------------------------------
// K5b: head GEMM, fixed. M=32, N=256, K=1088 in 17 steps of 64.
// A staged per-step (coalesced: 8 lanes cover one row's 128B), B from
// lane-ordered P2 (global load, LDS store, LDS frag-read all linear ->
// zero bank conflicts). Double-buffered, ONE barrier per step (next-step
// stores target the opposite buffer; barrier ordering proof in comments).
// 76KB LDS -> 2 blocks/CU; 512 blocks/slab = 1 generation. XCD swizzle.
// ---------------------------------------------------------------------------
__global__ __launch_bounds__(256, 2) void k5b_head(
    const unsigned short* __restrict__ hbi,   // ATF rows, stride NWS_
    const uint4* __restrict__ P2,             // [17*2048] lane-ordered frags
    const float* __restrict__ bg1, const float* __restrict__ Wg2,
    const float* __restrict__ bg2,
    float* __restrict__ out, int nwg)
{
    __shared__ __align__(16) unsigned short As[2][32*72];  // 9 KB
    __shared__ __align__(16) uint4 Bs[2][2048];            // 64 KB
    __shared__ float red[4][32];
    int tid = threadIdx.x, lane = tid & 63, wv = tid >> 6;
    int lr = lane & 15, kg = lane >> 4;

    int bid = blockIdx.x;
    int cpx = nwg >> 3;
    int tile = (bid & 7) * cpx + (bid >> 3);
    int row0 = tile * 32;

    int ar = tid >> 3, aseg = tid & 7;     // 32 rows x 8 threads, 16B each
    const unsigned short* asrc = &hbi[(size_t)(row0 + ar)*NWS_ + aseg*8];

    f32x4 acc[2][4];
    #pragma unroll
    for (int m = 0; m < 2; m++)
        #pragma unroll
        for (int n = 0; n < 4; n++) acc[m][n] = (f32x4){0.f,0.f,0.f,0.f};

    uint4 rA = *(const uint4*)asrc;        // step 0 A
    uint4 rB[8];
    #pragma unroll
    for (int j = 0; j < 8; j++) rB[j] = P2[j*256 + tid];   // step 0 B

    for (int s = 0; s < 17; s++) {
        unsigned short* Ac = As[s & 1];
        uint4* Bc = Bs[s & 1];
        *(uint4*)&Ac[ar*72 + aseg*8] = rA;
        #pragma unroll
        for (int j = 0; j < 8; j++) Bc[j*256 + tid] = rB[j];
        if (s < 16) {
            rA = *(const uint4*)(asrc + (s+1)*64);
            const uint4* ps = P2 + (s+1)*2048 + tid;
            #pragma unroll
            for (int j = 0; j < 8; j++) rB[j] = ps[j*256];
        }
        // ONE barrier: next iteration's stores hit buffer (s+1)&1, whose
        // last readers were iteration s-1; passing barrier(s) implies all
        // waves finished compute(s-1) (it precedes stores(s) in program
        // order). So no wave can still read buffer (s+1)&1 here.
        __syncthreads();
        #pragma unroll
        for (int kk = 0; kk < 2; kk++) {
            bf16x8 af0 = *(const bf16x8*)&Ac[lr*72      + kk*32 + kg*8];
            bf16x8 af1 = *(const bf16x8*)&Ac[(16+lr)*72 + kk*32 + kg*8];
            #pragma unroll
            for (int n = 0; n < 4; n++) {
                bf16x8 bf = *(const bf16x8*)&Bc[(kk*16 + wv*4 + n)*64 + lane];
                acc[0][n] = __builtin_amdgcn_mfma_f32_16x16x32_bf16(af0, bf, acc[0][n], 0, 0, 0);
                acc[1][n] = __builtin_amdgcn_mfma_f32_16x16x32_bf16(af1, bf, acc[1][n], 0, 0, 0);
            }
        }
    }

    // epilogue: gelu + *Wg2, reduce over this wave's 64 cols
    float rsum[2][4] = {{0.f,0.f,0.f,0.f},{0.f,0.f,0.f,0.f}};
    #pragma unroll
    for (int n = 0; n < 4; n++) {
        int colg = wv*64 + n*16 + lr;
        float bgv = bg1[colg], w2v = Wg2[colg];
        #pragma unroll
        for (int m = 0; m < 2; m++)
            #pragma unroll
            for (int r = 0; r < 4; r++) {
                float gv = gelu_f(acc[m][n][r] + bgv);
                rsum[m][r] = fmaf(gv, w2v, rsum[m][r]);
            }
    }
    #pragma unroll
    for (int off = 1; off < 16; off <<= 1)
        #pragma unroll
        for (int m = 0; m < 2; m++)
            #pragma unroll
            for (int r = 0; r < 4; r++)
                rsum[m][r] += __shfl_xor(rsum[m][r], off, 64);
    if (lr == 0) {
        #pragma unroll
        for (int m = 0; m < 2; m++)
            #pragma unroll
            for (int r = 0; r < 4; r++)
                red[wv][m*16 + kg*4 + r] = rsum[m][r];
    }
    __syncthreads();
    if (tid < 32)
        out[row0 + tid] = red[0][tid] + red[1][tid] + red[2][tid] + red[3][tid] + bg2[0];
}

// ---------------------------------------------------------------------------
extern "C" void kernel_launch(void* const* d_in, const int* in_sizes, int n_in,
                              void* d_out, int out_size, void* d_ws, size_t ws_size,
                              hipStream_t stream)
{
    const float* x    = (const float*)d_in[0];
    const float* t    = (const float*)d_in[1];
    const float* Wt1  = (const float*)d_in[2];
    const float* bt1  = (const float*)d_in[3];
    const float* Wt2  = (const float*)d_in[4];
    const float* bt2  = (const float*)d_in[5];
    const float* Wpf  = (const float*)d_in[6];
    const float* bpf  = (const float*)d_in[7];
    const float* Wpb  = (const float*)d_in[8];
    const float* bpb  = (const float*)d_in[9];
    const float* Wzf  = (const float*)d_in[10];
    const float* bzf  = (const float*)d_in[11];
    const float* Whf  = (const float*)d_in[12];
    const float* bhf  = (const float*)d_in[13];
    const float* Wzb  = (const float*)d_in[14];
    const float* bzb  = (const float*)d_in[15];
    const float* Whb  = (const float*)d_in[16];
    const float* bhb  = (const float*)d_in[17];
    const float* ln_g = (const float*)d_in[18];
    const float* ln_b = (const float*)d_in[19];
    const float* tsc  = (const float*)d_in[20];
    const float* Wg1  = (const float*)d_in[21];
    const float* bg1  = (const float*)d_in[22];
    const float* Wg2  = (const float*)d_in[23];
    const float* bg2  = (const float*)d_in[24];
    float* out = (float*)d_out;

    char* p = (char*)d_ws;
    auto carve = [&](size_t bytes) -> char* {
        char* q = p; p += (bytes + 255) & ~(size_t)255; return q;
    };

    unsigned short* WTf = (unsigned short*)carve((size_t)2*H_*H_*2);
    unsigned short* WTb = (unsigned short*)carve((size_t)2*H_*H_*2);
    uint4*          Pg2 = (uint4*)carve((size_t)17*2048*16);

    const size_t perBatch = (size_t)L_*H_*2            // inp
                          + (size_t)L_*NWS_*2*2        // ATF + ATB
                          + (size_t)L_*NT_*4           // tenc
                          + (size_t)CH_*H_*4*3*2;      // carries
    size_t fixedUsed = (size_t)(p - (char*)d_ws) + 64*1024;
    int NB = B_;
    while (NB > 1 && fixedUsed + (size_t)NB*perBatch > ws_size) NB >>= 1;

    unsigned short* inp = (unsigned short*)carve((size_t)NB*L_*H_*2);
    unsigned short* ATF = (unsigned short*)carve((size_t)NB*L_*NWS_*2);
    unsigned short* ATB = (unsigned short*)carve((size_t)NB*L_*NWS_*2);
    float* tenc   = (float*)carve((size_t)NB*L_*NT_*4);
    float* Scar   = (float*)carve((size_t)2*NB*CH_*H_*4);
    float* Pcar   = (float*)carve((size_t)2*NB*CH_*H_*4);
    float* Hstart = (float*)carve((size_t)2*NB*CH_*H_*4);

    {
        dim3 g(H_/32, H_/32);
        kT<<<g, 256, 0, stream>>>(Wzf, WTf,         H_, H_, H_);
        kT<<<g, 256, 0, stream>>>(Whf, WTf + H_*H_, H_, H_, H_);
        kT<<<g, 256, 0, stream>>>(Wzb, WTb,         H_, H_, H_);
        kT<<<g, 256, 0, stream>>>(Whb, WTb + H_*H_, H_, H_, H_);
        kP2<<<136, 256, 0, stream>>>(Wg1, Pg2);
    }

    for (int b0 = 0; b0 < B_; b0 += NB) {
        int rows = NB * L_;
        int nwg3 = (rows/128) * 8;

        k1_tenc_inp<<<rows/4, 256, 0, stream>>>(
            x + (size_t)b0*L_*2, t + (size_t)b0*L_,
            Wt1, bt1, Wt2, bt2, Wpf, bpf, tenc, inp);
        k3g<<<nwg3, 256, 0, stream>>>(inp, WTf, ATF, nwg3);

        k1_tenc_inp<<<rows/4, 256, 0, stream>>>(
            x + (size_t)b0*L_*2, t + (size_t)b0*L_,
            Wt1, bt1, Wt2, bt2, Wpb, bpb, tenc, inp);
        k3g<<<nwg3, 256, 0, stream>>>(inp, WTb, ATB, nwg3);

        int scanThreads = 2*NB*H_*CH_;
        k4a<<<scanThreads/256, 256, 0, stream>>>(ATF, ATB, bzf, bhf, bzb, bhb,
                                                 Scar, Pcar, NB);
        k4b<<<(2*NB*H_)/256, 256, 0, stream>>>(Scar, Pcar, Hstart, NB);

        k5a_ln<<<rows/4, 256, 0, stream>>>(ATF, ATB, Hstart, tenc,
                                           ln_g, ln_b, tsc, NB);

        int nwg5 = rows/32;
        k5b_head<<<nwg5, 256, 0, stream>>>(ATF, Pg2, bg1, Wg2, bg2,
                                           out + (size_t)b0*L_, nwg5);
    }
}

// Round 13
// 293.080 us; speedup vs baseline: 1.4658x; 1.3904x over previous
//
#include <hip/hip_runtime.h>
#include <hip/hip_bf16.h>
#include <math.h>

#define B_    16
#define L_    2048
#define H_    512
#define NT_   8
#define OUT_  1032
#define HEAD_ 256
#define CH_   16
#define CL_   (L_/CH_)   // 128
#define NWS_  1152       // AT row stride in shorts (z|h -> S|PP in place)

// k5 A-LDS geometry: 32 rows, 136 chunks of 16B (2176B row), XOR-swizzled
#define ACH_  136
#define ASTR_ (ACH_*8)   // shorts per row = 1088
#define RB5_  32         // rows per k5 block

typedef short bf16x8 __attribute__((ext_vector_type(8)));
typedef float f32x4  __attribute__((ext_vector_type(4)));

__device__ __forceinline__ float b2f(unsigned short u) {
    union { unsigned int u32; float f; } v; v.u32 = ((unsigned int)u) << 16; return v.f;
}
__device__ __forceinline__ unsigned short f2b(float f) {
    __hip_bfloat16 h = __float2bfloat16(f);
    return *reinterpret_cast<unsigned short*>(&h);
}
__device__ __forceinline__ float sigmoid_f(float x) {
    return 1.f / (1.f + exp2f(-1.44269504f * x));
}
__device__ __forceinline__ float tanh_f(float x) {
    float e = exp2f(2.88539008f * x);
    return 1.f - 2.f / (e + 1.f);
}
__device__ __forceinline__ float gelu_f(float g) {
    float u  = 0.70710678118654752f * g;
    float ax = fabsf(u);
    float t  = 1.f / (1.f + 0.3275911f * ax);
    float poly = ((((1.061405429f*t - 1.453152027f)*t + 1.421413741f)*t
                   - 0.284496736f)*t + 0.254829592f)*t;
    float e  = exp2f(-1.44269504f * ax * ax);
    float er = 1.f - poly * e;
    er = (u < 0.f) ? -er : er;
    return 0.5f * g * (1.f + er);
}

// ---------------------------------------------------------------------------
// kT: transpose + f32->bf16. in f32 [R][C] -> out bf16 [C][RP], zero r>=R.
// ---------------------------------------------------------------------------
__global__ __launch_bounds__(256) void kT(const float* __restrict__ in,
                                          unsigned short* __restrict__ out,
                                          int R, int C, int RP)
{
    __shared__ float tile[32][33];
    int c0 = blockIdx.x * 32, r0 = blockIdx.y * 32;
    int tx = threadIdx.x & 31, ty = threadIdx.x >> 5;
    #pragma unroll
    for (int j = 0; j < 32; j += 8) {
        int r = r0 + ty + j, c = c0 + tx;
        tile[ty + j][tx] = (r < R && c < C) ? in[(size_t)r*C + c] : 0.f;
    }
    __syncthreads();
    #pragma unroll
    for (int j = 0; j < 32; j += 8) {
        int c = c0 + ty + j, r = r0 + tx;
        if (c < C && r < RP) out[(size_t)c*RP + r] = f2b(tile[tx][ty + j]);
    }
}

// ---------------------------------------------------------------------------
// kP: pack Wg1 (f32 [OUT_][256]) into MFMA B-fragment chunks, 33 K-blocks:
// P[kb*1024 + c*4 + kg] = bf16 Wg1[kb*32+kg*8 .. +8][c]  (zero for k>=OUT_)
// ---------------------------------------------------------------------------
__global__ __launch_bounds__(256) void kP(const float* __restrict__ Wg1,
                                          uint4* __restrict__ P)
{
    int idx = blockIdx.x*256 + threadIdx.x;
    if (idx >= 33*1024) return;
    int kb = idx >> 10;
    int rem = idx & 1023;
    int c  = rem >> 2;
    int kg = rem & 3;
    int k0 = kb*32 + kg*8;
    unsigned short o[8];
    #pragma unroll
    for (int j = 0; j < 8; j++) {
        int k = k0 + j;
        o[j] = (k < OUT_) ? f2b(Wg1[(size_t)k*HEAD_ + c]) : (unsigned short)0;
    }
    P[idx] = *(const uint4*)o;
}

// ---------------------------------------------------------------------------
// K1 (per-dir): t_enc MLP + inp = xc @ Wp + bp. wave-per-row.
// ---------------------------------------------------------------------------
__global__ __launch_bounds__(256) void k1_tenc_inp(
    const float* __restrict__ x, const float* __restrict__ t,
    const float* __restrict__ Wt1, const float* __restrict__ bt1,
    const float* __restrict__ Wt2, const float* __restrict__ bt2,
    const float* __restrict__ Wp, const float* __restrict__ bp,
    float* __restrict__ t_enc,
    unsigned short* __restrict__ inp)
{
    int wv = threadIdx.x >> 6, lane = threadIdx.x & 63;
    size_t row = (size_t)blockIdx.x*4 + wv;
    float tv = t[row];
    float r1[NT_], te[NT_];
    #pragma unroll
    for (int k = 0; k < NT_; k++) r1[k] = fmaxf(tv*Wt1[k] + bt1[k], 0.f);
    #pragma unroll
    for (int j = 0; j < NT_; j++) {
        float a = bt2[j];
        #pragma unroll
        for (int k = 0; k < NT_; k++) a = fmaf(r1[k], Wt2[k*NT_+j], a);
        te[j] = a;
    }
    if (lane < NT_) t_enc[row*NT_ + lane] = te[lane];
    float x0 = x[row*2+0], x1 = x[row*2+1];
    int c0 = lane*8;
    float af[8];
    #pragma unroll
    for (int j = 0; j < 8; j++) {
        int c = c0 + j;
        af[j] = fmaf(x0, Wp[c], fmaf(x1, Wp[H_+c], bp[c]));
    }
    #pragma unroll
    for (int k = 0; k < NT_; k++) {
        #pragma unroll
        for (int j = 0; j < 8; j++)
            af[j] = fmaf(te[k], Wp[(2+k)*H_+c0+j], af[j]);
    }
    unsigned short of[8];
    #pragma unroll
    for (int j = 0; j < 8; j++) of[j] = f2b(af[j]);
    *(uint4*)&inp[row*H_ + c0] = *(const uint4*)of;
}

// ---------------------------------------------------------------------------
// K3g: PURE GEMM. AT[row][0..511] = inp@Wz (raw), AT[row][512..1023] = inp@Wh.
// 128x128 tile, BK=32, 80B-pad LDS, register prefetch, XCD remap.
// ---------------------------------------------------------------------------
__global__ __launch_bounds__(256) void k3g(
    const unsigned short* __restrict__ inp,   // [M][512] bf16
    const unsigned short* __restrict__ WT,    // [1024][512] bf16 (Wz rows, Wh rows)
    unsigned short* __restrict__ zt_out,      // [M][NWS_] bf16
    int nwg)
{
    __shared__ __align__(16) unsigned short As[128*40];
    __shared__ __align__(16) unsigned short Bs[128*40];
    int tid = threadIdx.x;
    int lane = tid & 63, w = tid >> 6;
    int wm = w >> 1, wn = w & 1;
    int kg = lane >> 4, lr = lane & 15;

    int bid = blockIdx.x;
    int cpx = nwg >> 3;
    int tile = (bid & 7) * cpx + (bid >> 3);
    int row0 = (tile >> 3) * 128;
    int n0   = (tile & 7) * 128;

    f32x4 acc[4][4];
    #pragma unroll
    for (int m = 0; m < 4; m++)
        #pragma unroll
        for (int n = 0; n < 4; n++) acc[m][n] = (f32x4){0.f,0.f,0.f,0.f};

    int ar = tid >> 1, aseg = tid & 1;

    uint4 va0, va1, vb0, vb1;
    {
        const uint4* ga = (const uint4*)&inp[(size_t)(row0+ar)*H_ + aseg*16];
        va0 = ga[0]; va1 = ga[1];
        const uint4* gb = (const uint4*)&WT[(size_t)(n0+ar)*H_ + aseg*16];
        vb0 = gb[0]; vb1 = gb[1];
    }

    for (int k0 = 0; k0 < H_; k0 += 32) {
        __syncthreads();
        *(uint4*)&As[ar*40 + aseg*16]     = va0;
        *(uint4*)&As[ar*40 + aseg*16 + 8] = va1;
        *(uint4*)&Bs[ar*40 + aseg*16]     = vb0;
        *(uint4*)&Bs[ar*40 + aseg*16 + 8] = vb1;
        __syncthreads();
        if (k0 + 32 < H_) {
            const uint4* ga = (const uint4*)&inp[(size_t)(row0+ar)*H_ + k0+32 + aseg*16];
            va0 = ga[0]; va1 = ga[1];
            const uint4* gb = (const uint4*)&WT[(size_t)(n0+ar)*H_ + k0+32 + aseg*16];
            vb0 = gb[0]; vb1 = gb[1];
        }
        bf16x8 af[4], bf[4];
        #pragma unroll
        for (int m = 0; m < 4; m++)
            af[m] = *(const bf16x8*)&As[(wm*64 + m*16 + lr)*40 + kg*8];
        #pragma unroll
        for (int n = 0; n < 4; n++)
            bf[n] = *(const bf16x8*)&Bs[(wn*64 + n*16 + lr)*40 + kg*8];
        #pragma unroll
        for (int m = 0; m < 4; m++)
            #pragma unroll
            for (int n = 0; n < 4; n++)
                acc[m][n] = __builtin_amdgcn_mfma_f32_16x16x32_bf16(af[m], bf[n], acc[m][n], 0, 0, 0);
    }

    #pragma unroll
    for (int m = 0; m < 4; m++)
        #pragma unroll
        for (int n = 0; n < 4; n++) {
            int colg = n0 + wn*64 + n*16 + lr;
            #pragma unroll
            for (int r = 0; r < 4; r++) {
                int rowg = row0 + wm*64 + m*16 + kg*4 + r;
                zt_out[(size_t)rowg*NWS_ + colg] = f2b(acc[m][n][r]);
            }
        }
}

// ---------------------------------------------------------------------------
// K4a: bias + activations + chunked scan pass A, in place on AT rows.
// ---------------------------------------------------------------------------
__global__ __launch_bounds__(256) void k4a(
    unsigned short* __restrict__ ATF, unsigned short* __restrict__ ATB,
    const float* __restrict__ bzf, const float* __restrict__ bhf,
    const float* __restrict__ bzb, const float* __restrict__ bhb,
    float* __restrict__ Scar, float* __restrict__ Pcar, int nb)
{
    int g = blockIdx.x*256 + threadIdx.x;
    int col   = g & (H_-1);
    int chunk = (g >> 9) & (CH_-1);
    int rest  = g >> 13;
    int bb    = rest % nb;
    int dir   = rest / nb;
    unsigned short* AT = dir ? ATB : ATF;
    float bzv = (dir ? bzb : bzf)[col];
    float bhv = (dir ? bhb : bhf)[col];
    size_t base = (size_t)bb * L_ * NWS_ + col;
    float h = 0.f, pp = 1.f;
    if (dir == 0) {
        int lo = chunk * CL_;
        for (int p = 0; p < CL_; p += 8) {
            unsigned short zv[8], hv[8];
            #pragma unroll
            for (int j = 0; j < 8; j++) {
                size_t idx = base + (size_t)(lo+p+j)*NWS_;
                zv[j] = AT[idx]; hv[j] = AT[idx + H_];
            }
            #pragma unroll
            for (int j = 0; j < 8; j++) {
                size_t idx = base + (size_t)(lo+p+j)*NWS_;
                float zg = sigmoid_f(b2f(zv[j]) + bzv);
                float a  = 1.f - zg;
                float bg = zg * tanh_f(b2f(hv[j]) + bhv);
                AT[idx]      = f2b(h);
                AT[idx + H_] = f2b(pp);
                h = fmaf(a, h, bg);
                pp *= a;
            }
        }
    } else {
        int hi = chunk * CL_ + CL_ - 1;
        for (int p = 0; p < CL_; p += 8) {
            unsigned short zv[8], hv[8];
            #pragma unroll
            for (int j = 0; j < 8; j++) {
                size_t idx = base + (size_t)(hi-p-j)*NWS_;
                zv[j] = AT[idx]; hv[j] = AT[idx + H_];
            }
            #pragma unroll
            for (int j = 0; j < 8; j++) {
                size_t idx = base + (size_t)(hi-p-j)*NWS_;
                float zg = sigmoid_f(b2f(zv[j]) + bzv);
                float a  = 1.f - zg;
                float bg = zg * tanh_f(b2f(hv[j]) + bhv);
                AT[idx]      = f2b(h);
                AT[idx + H_] = f2b(pp);
                h = fmaf(a, h, bg);
                pp *= a;
            }
        }
    }
    int ci = ((dir*nb + bb)*CH_ + chunk)*H_ + col;
    Scar[ci] = h; Pcar[ci] = pp;
}

// K4b: chain carries across chunks.
__global__ __launch_bounds__(256) void k4b(
    const float* __restrict__ Scar, const float* __restrict__ Pcar,
    float* __restrict__ Hstart, int nb)
{
    int g = blockIdx.x*256 + threadIdx.x;
    int col  = g & (H_-1);
    int rest = g >> 9;
    int bb   = rest % nb;
    int dir  = rest / nb;
    int baseci = (dir*nb + bb)*CH_;
    float h = 0.f;
    if (dir == 0) {
        for (int c = 0; c < CH_; c++) {
            int ci = (baseci + c)*H_ + col;
            Hstart[ci] = h;
            h = Scar[ci] + Pcar[ci]*h;
        }
    } else {
        for (int c = CH_-1; c >= 0; c--) {
            int ci = (baseci + c)*H_ + col;
            Hstart[ci] = h;
            h = Scar[ci] + Pcar[ci]*h;
        }
    }
}

// ---------------------------------------------------------------------------
// K5 fused (round-6 proven structure, AT-sourced gates): per 32-row block,
// h = S + PP*h0 + LN(1032) + affine + ts -> XOR-swizzled LDS A (no hbi in
// HBM, WRITE~0), then barrier-free head GEMM with fragment-packed coalesced
// P loads (2-deep register pipeline), gelu*Wg2 + shfl row-reduce epilogue.
// ---------------------------------------------------------------------------
__global__ __launch_bounds__(256) void k5_fused(
    const unsigned short* __restrict__ ATF, const unsigned short* __restrict__ ATB,
    const float* __restrict__ Hstart,
    const float* __restrict__ tenc,
    const float* __restrict__ ln_g, const float* __restrict__ ln_b,
    const float* __restrict__ tsp,
    const uint4* __restrict__ P,              // [33*1024] packed Wg1 fragments
    const float* __restrict__ bg1, const float* __restrict__ Wg2,
    const float* __restrict__ bg2,
    float* __restrict__ out, int nb)
{
    __shared__ __align__(16) unsigned short A[RB5_*ASTR_];   // 68 KB
    __shared__ float red[4][RB5_];
    int tid = threadIdx.x, lane = tid & 63, wv = tid >> 6;
    int kg = lane >> 4, lr = lane & 15;
    int row0 = blockIdx.x * RB5_;
    float ts = tsp[0];

    int bb    = row0 >> 11;          // / L_
    int chunk = (row0 & (L_-1)) >> 7;
    int cif = (bb*CH_ + chunk)*H_;
    int cib = ((nb + bb)*CH_ + chunk)*H_;
    int c0 = lane*8;
    float4 hfa = *(const float4*)&Hstart[cif + c0];
    float4 hfb = *(const float4*)&Hstart[cif + c0 + 4];
    float4 hba = *(const float4*)&Hstart[cib + c0];
    float4 hbb = *(const float4*)&Hstart[cib + c0 + 4];
    float h0f[8] = {hfa.x,hfa.y,hfa.z,hfa.w,hfb.x,hfb.y,hfb.z,hfb.w};
    float h0b[8] = {hba.x,hba.y,hba.z,hba.w,hbb.x,hbb.y,hbb.z,hbb.w};

    float gf[8], bf_[8], gb_[8], bb_[8];
    #pragma unroll
    for (int j = 0; j < 8; j++) {
        gf[j]  = ln_g[c0+j];     bf_[j] = ln_b[c0+j];
        gb_[j] = ln_g[H_+c0+j];  bb_[j] = ln_b[H_+c0+j];
    }
    float gt = 0.f, bt = 0.f;
    if (lane < NT_) { gt = ln_g[2*H_+lane]; bt = ln_b[2*H_+lane]; }

    #pragma unroll
    for (int i = 0; i < 8; i++) {
        int r = wv*8 + i;
        size_t row = (size_t)row0 + r;
        size_t rb = row * NWS_;
        uint4 SF = *(const uint4*)&ATF[rb + c0];
        uint4 PF = *(const uint4*)&ATF[rb + H_ + c0];
        uint4 SB = *(const uint4*)&ATB[rb + c0];
        uint4 PB = *(const uint4*)&ATB[rb + H_ + c0];
        const unsigned short* sf = (const unsigned short*)&SF;
        const unsigned short* pf = (const unsigned short*)&PF;
        const unsigned short* sb = (const unsigned short*)&SB;
        const unsigned short* pb = (const unsigned short*)&PB;
        float fv[8], bv[8];
        float S = 0.f, Q = 0.f;
        #pragma unroll
        for (int j = 0; j < 8; j++) {
            fv[j] = fmaf(b2f(pf[j]), h0f[j], b2f(sf[j]));
            S += fv[j]; Q += fv[j]*fv[j];
            bv[j] = fmaf(b2f(pb[j]), h0b[j], b2f(sb[j]));
            S += bv[j]; Q += bv[j]*bv[j];
        }
        float tv = 0.f;
        if (lane < NT_) { tv = tenc[row*NT_ + lane]; S += tv; Q += tv*tv; }
        #pragma unroll
        for (int off = 32; off > 0; off >>= 1) {
            S += __shfl_xor(S, off, 64);
            Q += __shfl_xor(Q, off, 64);
        }
        float mu = S * (1.f/1032.f);
        float rs = rsqrtf(Q * (1.f/1032.f) - mu*mu + 1e-5f);
        int key = r & 7;
        unsigned short o[8];
        #pragma unroll
        for (int j = 0; j < 8; j++) o[j] = f2b((fv[j]-mu)*rs*gf[j] + bf_[j]);
        *(uint4*)&A[r*ASTR_ + ((lane ^ key)*8)] = *(const uint4*)o;
        #pragma unroll
        for (int j = 0; j < 8; j++) o[j] = f2b((bv[j]-mu)*rs*gb_[j] + bb_[j]);
        *(uint4*)&A[r*ASTR_ + (((64+lane) ^ key)*8)] = *(const uint4*)o;
        if (lane < NT_) {
            // chunk 128: cols 1024..1031 (tenc part)
            A[r*ASTR_ + ((128 ^ key)*8) + lane] =
                f2b(((tv-mu)*rs*gt + bt) * ts);
        } else {
            // chunks 129..135: cols 1032..1087 zero (lanes 8..63)
            int cc = 128 + (lane >> 3);
            A[r*ASTR_ + ((cc ^ key)*8) + (lane & 7)] = 0;
        }
    }
    __syncthreads();

    // ---- GEMM phase (no barriers, 2-deep B pipeline) ----
    f32x4 acc[2][4];
    #pragma unroll
    for (int m = 0; m < 2; m++)
        #pragma unroll
        for (int n = 0; n < 4; n++) acc[m][n] = (f32x4){0.f,0.f,0.f,0.f};

    const uint4* Pw = P + wv*256 + lr*4 + kg;
    int keyA = lr & 7;

#define LOADB(v0,v1,v2,v3,KB) do { \
        const uint4* q_ = Pw + (KB)*1024; \
        v0 = *(const bf16x8*)&q_[0]; \
        v1 = *(const bf16x8*)&q_[64]; \
        v2 = *(const bf16x8*)&q_[128]; \
        v3 = *(const bf16x8*)&q_[192]; \
    } while(0)
#define LDSA0(KB) (*(const bf16x8*)&A[lr*ASTR_      + ((((KB)*4+kg) ^ keyA)*8)])
#define LDSA1(KB) (*(const bf16x8*)&A[(16+lr)*ASTR_ + ((((KB)*4+kg) ^ keyA)*8)])
#define MFMA8(v0,v1,v2,v3,a0_,a1_) do { \
        acc[0][0] = __builtin_amdgcn_mfma_f32_16x16x32_bf16(a0_, v0, acc[0][0],0,0,0); \
        acc[0][1] = __builtin_amdgcn_mfma_f32_16x16x32_bf16(a0_, v1, acc[0][1],0,0,0); \
        acc[0][2] = __builtin_amdgcn_mfma_f32_16x16x32_bf16(a0_, v2, acc[0][2],0,0,0); \
        acc[0][3] = __builtin_amdgcn_mfma_f32_16x16x32_bf16(a0_, v3, acc[0][3],0,0,0); \
        acc[1][0] = __builtin_amdgcn_mfma_f32_16x16x32_bf16(a1_, v0, acc[1][0],0,0,0); \
        acc[1][1] = __builtin_amdgcn_mfma_f32_16x16x32_bf16(a1_, v1, acc[1][1],0,0,0); \
        acc[1][2] = __builtin_amdgcn_mfma_f32_16x16x32_bf16(a1_, v2, acc[1][2],0,0,0); \
        acc[1][3] = __builtin_amdgcn_mfma_f32_16x16x32_bf16(a1_, v3, acc[1][3],0,0,0); \
    } while(0)

    bf16x8 a0,a1,a2,a3, d0,d1,d2,d3;
    LOADB(a0,a1,a2,a3, 0);
    for (int kb = 0; kb < 32; kb += 2) {
        LOADB(d0,d1,d2,d3, kb+1);
        bf16x8 af0 = LDSA0(kb), af1 = LDSA1(kb);
        MFMA8(a0,a1,a2,a3, af0, af1);
        LOADB(a0,a1,a2,a3, kb+2);
        af0 = LDSA0(kb+1); af1 = LDSA1(kb+1);
        MFMA8(d0,d1,d2,d3, af0, af1);
    }
    {
        bf16x8 af0 = LDSA0(32), af1 = LDSA1(32);
        MFMA8(a0,a1,a2,a3, af0, af1);
    }
#undef LOADB
#undef LDSA0
#undef LDSA1
#undef MFMA8

    // ---- epilogue: gelu + *Wg2, reduce over this wave's 64 cols ----
    float rsum[2][4] = {{0.f,0.f,0.f,0.f},{0.f,0.f,0.f,0.f}};
    #pragma unroll
    for (int n = 0; n < 4; n++) {
        int colg = wv*64 + n*16 + lr;
        float bgv = bg1[colg], w2v = Wg2[colg];
        #pragma unroll
        for (int m = 0; m < 2; m++)
            #pragma unroll
            for (int r = 0; r < 4; r++) {
                float gv = gelu_f(acc[m][n][r] + bgv);
                rsum[m][r] = fmaf(gv, w2v, rsum[m][r]);
            }
    }
    #pragma unroll
    for (int off = 1; off < 16; off <<= 1)
        #pragma unroll
        for (int m = 0; m < 2; m++)
            #pragma unroll
            for (int r = 0; r < 4; r++)
                rsum[m][r] += __shfl_xor(rsum[m][r], off, 64);
    if (lr == 0) {
        #pragma unroll
        for (int m = 0; m < 2; m++)
            #pragma unroll
            for (int r = 0; r < 4; r++)
                red[wv][m*16 + kg*4 + r] = rsum[m][r];
    }
    __syncthreads();
    if (tid < RB5_)
        out[row0 + tid] = red[0][tid] + red[1][tid] + red[2][tid] + red[3][tid] + bg2[0];
}

// ---------------------------------------------------------------------------
extern "C" void kernel_launch(void* const* d_in, const int* in_sizes, int n_in,
                              void* d_out, int out_size, void* d_ws, size_t ws_size,
                              hipStream_t stream)
{
    const float* x    = (const float*)d_in[0];
    const float* t    = (const float*)d_in[1];
    const float* Wt1  = (const float*)d_in[2];
    const float* bt1  = (const float*)d_in[3];
    const float* Wt2  = (const float*)d_in[4];
    const float* bt2  = (const float*)d_in[5];
    const float* Wpf  = (const float*)d_in[6];
    const float* bpf  = (const float*)d_in[7];
    const float* Wpb  = (const float*)d_in[8];
    const float* bpb  = (const float*)d_in[9];
    const float* Wzf  = (const float*)d_in[10];
    const float* bzf  = (const float*)d_in[11];
    const float* Whf  = (const float*)d_in[12];
    const float* bhf  = (const float*)d_in[13];
    const float* Wzb  = (const float*)d_in[14];
    const float* bzb  = (const float*)d_in[15];
    const float* Whb  = (const float*)d_in[16];
    const float* bhb  = (const float*)d_in[17];
    const float* ln_g = (const float*)d_in[18];
    const float* ln_b = (const float*)d_in[19];
    const float* tsc  = (const float*)d_in[20];
    const float* Wg1  = (const float*)d_in[21];
    const float* bg1  = (const float*)d_in[22];
    const float* Wg2  = (const float*)d_in[23];
    const float* bg2  = (const float*)d_in[24];
    float* out = (float*)d_out;

    char* p = (char*)d_ws;
    auto carve = [&](size_t bytes) -> char* {
        char* q = p; p += (bytes + 255) & ~(size_t)255; return q;
    };

    unsigned short* WTf = (unsigned short*)carve((size_t)2*H_*H_*2);
    unsigned short* WTb = (unsigned short*)carve((size_t)2*H_*H_*2);
    uint4*          Pg  = (uint4*)carve((size_t)33*1024*16);

    const size_t perBatch = (size_t)L_*H_*2            // inp
                          + (size_t)L_*NWS_*2*2        // ATF + ATB
                          + (size_t)L_*NT_*4           // tenc
                          + (size_t)CH_*H_*4*3*2;      // carries
    size_t fixedUsed = (size_t)(p - (char*)d_ws) + 64*1024;
    int NB = B_;
    while (NB > 1 && fixedUsed + (size_t)NB*perBatch > ws_size) NB >>= 1;

    unsigned short* inp = (unsigned short*)carve((size_t)NB*L_*H_*2);
    unsigned short* ATF = (unsigned short*)carve((size_t)NB*L_*NWS_*2);
    unsigned short* ATB = (unsigned short*)carve((size_t)NB*L_*NWS_*2);
    float* tenc   = (float*)carve((size_t)NB*L_*NT_*4);
    float* Scar   = (float*)carve((size_t)2*NB*CH_*H_*4);
    float* Pcar   = (float*)carve((size_t)2*NB*CH_*H_*4);
    float* Hstart = (float*)carve((size_t)2*NB*CH_*H_*4);

    {
        dim3 g(H_/32, H_/32);
        kT<<<g, 256, 0, stream>>>(Wzf, WTf,         H_, H_, H_);
        kT<<<g, 256, 0, stream>>>(Whf, WTf + H_*H_, H_, H_, H_);
        kT<<<g, 256, 0, stream>>>(Wzb, WTb,         H_, H_, H_);
        kT<<<g, 256, 0, stream>>>(Whb, WTb + H_*H_, H_, H_, H_);
        kP<<<132, 256, 0, stream>>>(Wg1, Pg);
    }

    for (int b0 = 0; b0 < B_; b0 += NB) {
        int rows = NB * L_;
        int nwg3 = (rows/128) * 8;

        k1_tenc_inp<<<rows/4, 256, 0, stream>>>(
            x + (size_t)b0*L_*2, t + (size_t)b0*L_,
            Wt1, bt1, Wt2, bt2, Wpf, bpf, tenc, inp);
        k3g<<<nwg3, 256, 0, stream>>>(inp, WTf, ATF, nwg3);

        k1_tenc_inp<<<rows/4, 256, 0, stream>>>(
            x + (size_t)b0*L_*2, t + (size_t)b0*L_,
            Wt1, bt1, Wt2, bt2, Wpb, bpb, tenc, inp);
        k3g<<<nwg3, 256, 0, stream>>>(inp, WTb, ATB, nwg3);

        int scanThreads = 2*NB*H_*CH_;
        k4a<<<scanThreads/256, 256, 0, stream>>>(ATF, ATB, bzf, bhf, bzb, bhb,
                                                 Scar, Pcar, NB);
        k4b<<<(2*NB*H_)/256, 256, 0, stream>>>(Scar, Pcar, Hstart, NB);

        k5_fused<<<rows/RB5_, 256, 0, stream>>>(
            ATF, ATB, Hstart, tenc, ln_g, ln_b, tsc,
            Pg, bg1, Wg2, bg2, out + (size_t)b0*L_, NB);
    }
}

// Round 14
// 288.725 us; speedup vs baseline: 1.4879x; 1.0151x over previous
//
#include <hip/hip_runtime.h>
#include <hip/hip_bf16.h>
#include <math.h>

#define B_    16
#define L_    2048
#define H_    512
#define NT_   8
#define OUT_  1032
#define HEAD_ 256
#define CH_   16
#define CL_   (L_/CH_)   // 128
#define NWS_  1152       // AT row stride in shorts (z|h -> S|PP in place)

// k5 A-LDS geometry: 32 rows, 136 chunks of 16B (2176B row), XOR-swizzled
#define ACH_  136
#define ASTR_ (ACH_*8)   // shorts per row = 1088
#define RB5_  32         // rows per k5 block

typedef short bf16x8 __attribute__((ext_vector_type(8)));
typedef float f32x4  __attribute__((ext_vector_type(4)));

__device__ __forceinline__ float b2f(unsigned short u) {
    union { unsigned int u32; float f; } v; v.u32 = ((unsigned int)u) << 16; return v.f;
}
__device__ __forceinline__ unsigned short f2b(float f) {
    __hip_bfloat16 h = __float2bfloat16(f);
    return *reinterpret_cast<unsigned short*>(&h);
}
__device__ __forceinline__ float sigmoid_f(float x) {
    return 1.f / (1.f + exp2f(-1.44269504f * x));
}
__device__ __forceinline__ float tanh_f(float x) {
    float e = exp2f(2.88539008f * x);
    return 1.f - 2.f / (e + 1.f);
}
__device__ __forceinline__ float gelu_f(float g) {
    float u  = 0.70710678118654752f * g;
    float ax = fabsf(u);
    float t  = 1.f / (1.f + 0.3275911f * ax);
    float poly = ((((1.061405429f*t - 1.453152027f)*t + 1.421413741f)*t
                   - 0.284496736f)*t + 0.254829592f)*t;
    float e  = exp2f(-1.44269504f * ax * ax);
    float er = 1.f - poly * e;
    er = (u < 0.f) ? -er : er;
    return 0.5f * g * (1.f + er);
}

// ---------------------------------------------------------------------------
// kT: transpose + f32->bf16. in f32 [R][C] -> out bf16 [C][RP], zero r>=R.
// ---------------------------------------------------------------------------
__global__ __launch_bounds__(256) void kT(const float* __restrict__ in,
                                          unsigned short* __restrict__ out,
                                          int R, int C, int RP)
{
    __shared__ float tile[32][33];
    int c0 = blockIdx.x * 32, r0 = blockIdx.y * 32;
    int tx = threadIdx.x & 31, ty = threadIdx.x >> 5;
    #pragma unroll
    for (int j = 0; j < 32; j += 8) {
        int r = r0 + ty + j, c = c0 + tx;
        tile[ty + j][tx] = (r < R && c < C) ? in[(size_t)r*C + c] : 0.f;
    }
    __syncthreads();
    #pragma unroll
    for (int j = 0; j < 32; j += 8) {
        int c = c0 + ty + j, r = r0 + tx;
        if (c < C && r < RP) out[(size_t)c*RP + r] = f2b(tile[tx][ty + j]);
    }
}

// ---------------------------------------------------------------------------
// kP: pack Wg1 (f32 [OUT_][256]) into MFMA B-fragment chunks, 33 K-blocks:
// P[kb*1024 + c*4 + kg] = bf16 Wg1[kb*32+kg*8 .. +8][c]  (zero for k>=OUT_)
// ---------------------------------------------------------------------------
__global__ __launch_bounds__(256) void kP(const float* __restrict__ Wg1,
                                          uint4* __restrict__ P)
{
    int idx = blockIdx.x*256 + threadIdx.x;
    if (idx >= 33*1024) return;
    int kb = idx >> 10;
    int rem = idx & 1023;
    int c  = rem >> 2;
    int kg = rem & 3;
    int k0 = kb*32 + kg*8;
    unsigned short o[8];
    #pragma unroll
    for (int j = 0; j < 8; j++) {
        int k = k0 + j;
        o[j] = (k < OUT_) ? f2b(Wg1[(size_t)k*HEAD_ + c]) : (unsigned short)0;
    }
    P[idx] = *(const uint4*)o;
}

// ---------------------------------------------------------------------------
// K1 (per-dir): t_enc MLP + inp = xc @ Wp + bp. wave-per-row.
// ---------------------------------------------------------------------------
__global__ __launch_bounds__(256) void k1_tenc_inp(
    const float* __restrict__ x, const float* __restrict__ t,
    const float* __restrict__ Wt1, const float* __restrict__ bt1,
    const float* __restrict__ Wt2, const float* __restrict__ bt2,
    const float* __restrict__ Wp, const float* __restrict__ bp,
    float* __restrict__ t_enc,
    unsigned short* __restrict__ inp)
{
    int wv = threadIdx.x >> 6, lane = threadIdx.x & 63;
    size_t row = (size_t)blockIdx.x*4 + wv;
    float tv = t[row];
    float r1[NT_], te[NT_];
    #pragma unroll
    for (int k = 0; k < NT_; k++) r1[k] = fmaxf(tv*Wt1[k] + bt1[k], 0.f);
    #pragma unroll
    for (int j = 0; j < NT_; j++) {
        float a = bt2[j];
        #pragma unroll
        for (int k = 0; k < NT_; k++) a = fmaf(r1[k], Wt2[k*NT_+j], a);
        te[j] = a;
    }
    if (lane < NT_) t_enc[row*NT_ + lane] = te[lane];
    float x0 = x[row*2+0], x1 = x[row*2+1];
    int c0 = lane*8;
    float af[8];
    #pragma unroll
    for (int j = 0; j < 8; j++) {
        int c = c0 + j;
        af[j] = fmaf(x0, Wp[c], fmaf(x1, Wp[H_+c], bp[c]));
    }
    #pragma unroll
    for (int k = 0; k < NT_; k++) {
        #pragma unroll
        for (int j = 0; j < 8; j++)
            af[j] = fmaf(te[k], Wp[(2+k)*H_+c0+j], af[j]);
    }
    unsigned short of[8];
    #pragma unroll
    for (int j = 0; j < 8; j++) of[j] = f2b(af[j]);
    *(uint4*)&inp[row*H_ + c0] = *(const uint4*)of;
}

// ---------------------------------------------------------------------------
// K3g: PURE GEMM. AT[row][0..511] = inp@Wz (raw), AT[row][512..1023] = inp@Wh.
// 128x128 tile, BK=32, 80B-pad LDS, register prefetch, XCD remap.
// ---------------------------------------------------------------------------
__global__ __launch_bounds__(256) void k3g(
    const unsigned short* __restrict__ inp,   // [M][512] bf16
    const unsigned short* __restrict__ WT,    // [1024][512] bf16 (Wz rows, Wh rows)
    unsigned short* __restrict__ zt_out,      // [M][NWS_] bf16
    int nwg)
{
    __shared__ __align__(16) unsigned short As[128*40];
    __shared__ __align__(16) unsigned short Bs[128*40];
    int tid = threadIdx.x;
    int lane = tid & 63, w = tid >> 6;
    int wm = w >> 1, wn = w & 1;
    int kg = lane >> 4, lr = lane & 15;

    int bid = blockIdx.x;
    int cpx = nwg >> 3;
    int tile = (bid & 7) * cpx + (bid >> 3);
    int row0 = (tile >> 3) * 128;
    int n0   = (tile & 7) * 128;

    f32x4 acc[4][4];
    #pragma unroll
    for (int m = 0; m < 4; m++)
        #pragma unroll
        for (int n = 0; n < 4; n++) acc[m][n] = (f32x4){0.f,0.f,0.f,0.f};

    int ar = tid >> 1, aseg = tid & 1;

    uint4 va0, va1, vb0, vb1;
    {
        const uint4* ga = (const uint4*)&inp[(size_t)(row0+ar)*H_ + aseg*16];
        va0 = ga[0]; va1 = ga[1];
        const uint4* gb = (const uint4*)&WT[(size_t)(n0+ar)*H_ + aseg*16];
        vb0 = gb[0]; vb1 = gb[1];
    }

    for (int k0 = 0; k0 < H_; k0 += 32) {
        __syncthreads();
        *(uint4*)&As[ar*40 + aseg*16]     = va0;
        *(uint4*)&As[ar*40 + aseg*16 + 8] = va1;
        *(uint4*)&Bs[ar*40 + aseg*16]     = vb0;
        *(uint4*)&Bs[ar*40 + aseg*16 + 8] = vb1;
        __syncthreads();
        if (k0 + 32 < H_) {
            const uint4* ga = (const uint4*)&inp[(size_t)(row0+ar)*H_ + k0+32 + aseg*16];
            va0 = ga[0]; va1 = ga[1];
            const uint4* gb = (const uint4*)&WT[(size_t)(n0+ar)*H_ + k0+32 + aseg*16];
            vb0 = gb[0]; vb1 = gb[1];
        }
        bf16x8 af[4], bf[4];
        #pragma unroll
        for (int m = 0; m < 4; m++)
            af[m] = *(const bf16x8*)&As[(wm*64 + m*16 + lr)*40 + kg*8];
        #pragma unroll
        for (int n = 0; n < 4; n++)
            bf[n] = *(const bf16x8*)&Bs[(wn*64 + n*16 + lr)*40 + kg*8];
        #pragma unroll
        for (int m = 0; m < 4; m++)
            #pragma unroll
            for (int n = 0; n < 4; n++)
                acc[m][n] = __builtin_amdgcn_mfma_f32_16x16x32_bf16(af[m], bf[n], acc[m][n], 0, 0, 0);
    }

    #pragma unroll
    for (int m = 0; m < 4; m++)
        #pragma unroll
        for (int n = 0; n < 4; n++) {
            int colg = n0 + wn*64 + n*16 + lr;
            #pragma unroll
            for (int r = 0; r < 4; r++) {
                int rowg = row0 + wm*64 + m*16 + kg*4 + r;
                zt_out[(size_t)rowg*NWS_ + colg] = f2b(acc[m][n][r]);
            }
        }
}

// ---------------------------------------------------------------------------
// K4a: bias + activations + chunked scan pass A, in place on AT rows.
// ---------------------------------------------------------------------------
__global__ __launch_bounds__(256) void k4a(
    unsigned short* __restrict__ ATF, unsigned short* __restrict__ ATB,
    const float* __restrict__ bzf, const float* __restrict__ bhf,
    const float* __restrict__ bzb, const float* __restrict__ bhb,
    float* __restrict__ Scar, float* __restrict__ Pcar, int nb)
{
    int g = blockIdx.x*256 + threadIdx.x;
    int col   = g & (H_-1);
    int chunk = (g >> 9) & (CH_-1);
    int rest  = g >> 13;
    int bb    = rest % nb;
    int dir   = rest / nb;
    unsigned short* AT = dir ? ATB : ATF;
    float bzv = (dir ? bzb : bzf)[col];
    float bhv = (dir ? bhb : bhf)[col];
    size_t base = (size_t)bb * L_ * NWS_ + col;
    float h = 0.f, pp = 1.f;
    if (dir == 0) {
        int lo = chunk * CL_;
        for (int p = 0; p < CL_; p += 8) {
            unsigned short zv[8], hv[8];
            #pragma unroll
            for (int j = 0; j < 8; j++) {
                size_t idx = base + (size_t)(lo+p+j)*NWS_;
                zv[j] = AT[idx]; hv[j] = AT[idx + H_];
            }
            #pragma unroll
            for (int j = 0; j < 8; j++) {
                size_t idx = base + (size_t)(lo+p+j)*NWS_;
                float zg = sigmoid_f(b2f(zv[j]) + bzv);
                float a  = 1.f - zg;
                float bg = zg * tanh_f(b2f(hv[j]) + bhv);
                AT[idx]      = f2b(h);
                AT[idx + H_] = f2b(pp);
                h = fmaf(a, h, bg);
                pp *= a;
            }
        }
    } else {
        int hi = chunk * CL_ + CL_ - 1;
        for (int p = 0; p < CL_; p += 8) {
            unsigned short zv[8], hv[8];
            #pragma unroll
            for (int j = 0; j < 8; j++) {
                size_t idx = base + (size_t)(hi-p-j)*NWS_;
                zv[j] = AT[idx]; hv[j] = AT[idx + H_];
            }
            #pragma unroll
            for (int j = 0; j < 8; j++) {
                size_t idx = base + (size_t)(hi-p-j)*NWS_;
                float zg = sigmoid_f(b2f(zv[j]) + bzv);
                float a  = 1.f - zg;
                float bg = zg * tanh_f(b2f(hv[j]) + bhv);
                AT[idx]      = f2b(h);
                AT[idx + H_] = f2b(pp);
                h = fmaf(a, h, bg);
                pp *= a;
            }
        }
    }
    int ci = ((dir*nb + bb)*CH_ + chunk)*H_ + col;
    Scar[ci] = h; Pcar[ci] = pp;
}

// K4b: chain carries across chunks.
__global__ __launch_bounds__(256) void k4b(
    const float* __restrict__ Scar, const float* __restrict__ Pcar,
    float* __restrict__ Hstart, int nb)
{
    int g = blockIdx.x*256 + threadIdx.x;
    int col  = g & (H_-1);
    int rest = g >> 9;
    int bb   = rest % nb;
    int dir  = rest / nb;
    int baseci = (dir*nb + bb)*CH_;
    float h = 0.f;
    if (dir == 0) {
        for (int c = 0; c < CH_; c++) {
            int ci = (baseci + c)*H_ + col;
            Hstart[ci] = h;
            h = Scar[ci] + Pcar[ci]*h;
        }
    } else {
        for (int c = CH_-1; c >= 0; c--) {
            int ci = (baseci + c)*H_ + col;
            Hstart[ci] = h;
            h = Scar[ci] + Pcar[ci]*h;
        }
    }
}

// ---------------------------------------------------------------------------
// K5 fused (round-13 structure + rolling-1 LN prefetch + 3-deep B pipeline):
// per 32-row block, h = S + PP*h0 + LN(1032) + affine + ts -> XOR-swizzled
// LDS A (no hbi in HBM), then barrier-free head GEMM with fragment-packed
// coalesced P loads, gelu*Wg2 + shfl row-reduce epilogue.
// ---------------------------------------------------------------------------
__global__ __launch_bounds__(256) void k5_fused(
    const unsigned short* __restrict__ ATF, const unsigned short* __restrict__ ATB,
    const float* __restrict__ Hstart,
    const float* __restrict__ tenc,
    const float* __restrict__ ln_g, const float* __restrict__ ln_b,
    const float* __restrict__ tsp,
    const uint4* __restrict__ P,              // [33*1024] packed Wg1 fragments
    const float* __restrict__ bg1, const float* __restrict__ Wg2,
    const float* __restrict__ bg2,
    float* __restrict__ out, int nb)
{
    __shared__ __align__(16) unsigned short A[RB5_*ASTR_];   // 68 KB
    __shared__ float red[4][RB5_];
    int tid = threadIdx.x, lane = tid & 63, wv = tid >> 6;
    int kg = lane >> 4, lr = lane & 15;
    int row0 = blockIdx.x * RB5_;
    float ts = tsp[0];

    int bb    = row0 >> 11;          // / L_
    int chunk = (row0 & (L_-1)) >> 7;
    int cif = (bb*CH_ + chunk)*H_;
    int cib = ((nb + bb)*CH_ + chunk)*H_;
    int c0 = lane*8;
    float4 hfa = *(const float4*)&Hstart[cif + c0];
    float4 hfb = *(const float4*)&Hstart[cif + c0 + 4];
    float4 hba = *(const float4*)&Hstart[cib + c0];
    float4 hbb = *(const float4*)&Hstart[cib + c0 + 4];
    float h0f[8] = {hfa.x,hfa.y,hfa.z,hfa.w,hfb.x,hfb.y,hfb.z,hfb.w};
    float h0b[8] = {hba.x,hba.y,hba.z,hba.w,hbb.x,hbb.y,hbb.z,hbb.w};

    float gf[8], bf_[8], gb_[8], bb_[8];
    #pragma unroll
    for (int j = 0; j < 8; j++) {
        gf[j]  = ln_g[c0+j];     bf_[j] = ln_b[c0+j];
        gb_[j] = ln_g[H_+c0+j];  bb_[j] = ln_b[H_+c0+j];
    }
    float gt = 0.f, bt = 0.f;
    if (lane < NT_) { gt = ln_g[2*H_+lane]; bt = ln_b[2*H_+lane]; }

    // ---- LN phase with rolling-1 row prefetch ----
    size_t rowBase = (size_t)(row0 + wv*8) * NWS_;
    uint4 cSF = *(const uint4*)&ATF[rowBase + c0];
    uint4 cPF = *(const uint4*)&ATF[rowBase + H_ + c0];
    uint4 cSB = *(const uint4*)&ATB[rowBase + c0];
    uint4 cPB = *(const uint4*)&ATB[rowBase + H_ + c0];

    #pragma unroll
    for (int i = 0; i < 8; i++) {
        int r = wv*8 + i;
        size_t row = (size_t)row0 + r;
        uint4 SF = cSF, PF = cPF, SB = cSB, PB = cPB;
        if (i < 7) {
            size_t rb2 = rowBase + (size_t)(i+1)*NWS_;
            cSF = *(const uint4*)&ATF[rb2 + c0];
            cPF = *(const uint4*)&ATF[rb2 + H_ + c0];
            cSB = *(const uint4*)&ATB[rb2 + c0];
            cPB = *(const uint4*)&ATB[rb2 + H_ + c0];
        }
        const unsigned short* sf = (const unsigned short*)&SF;
        const unsigned short* pf = (const unsigned short*)&PF;
        const unsigned short* sb = (const unsigned short*)&SB;
        const unsigned short* pb = (const unsigned short*)&PB;
        float fv[8], bv[8];
        float S = 0.f, Q = 0.f;
        #pragma unroll
        for (int j = 0; j < 8; j++) {
            fv[j] = fmaf(b2f(pf[j]), h0f[j], b2f(sf[j]));
            S += fv[j]; Q += fv[j]*fv[j];
            bv[j] = fmaf(b2f(pb[j]), h0b[j], b2f(sb[j]));
            S += bv[j]; Q += bv[j]*bv[j];
        }
        float tv = 0.f;
        if (lane < NT_) { tv = tenc[row*NT_ + lane]; S += tv; Q += tv*tv; }
        #pragma unroll
        for (int off = 32; off > 0; off >>= 1) {
            S += __shfl_xor(S, off, 64);
            Q += __shfl_xor(Q, off, 64);
        }
        float mu = S * (1.f/1032.f);
        float rs = rsqrtf(Q * (1.f/1032.f) - mu*mu + 1e-5f);
        int key = r & 7;
        unsigned short o[8];
        #pragma unroll
        for (int j = 0; j < 8; j++) o[j] = f2b((fv[j]-mu)*rs*gf[j] + bf_[j]);
        *(uint4*)&A[r*ASTR_ + ((lane ^ key)*8)] = *(const uint4*)o;
        #pragma unroll
        for (int j = 0; j < 8; j++) o[j] = f2b((bv[j]-mu)*rs*gb_[j] + bb_[j]);
        *(uint4*)&A[r*ASTR_ + (((64+lane) ^ key)*8)] = *(const uint4*)o;
        if (lane < NT_) {
            // chunk 128: cols 1024..1031 (tenc part)
            A[r*ASTR_ + ((128 ^ key)*8) + lane] =
                f2b(((tv-mu)*rs*gt + bt) * ts);
        } else {
            // chunks 129..135: cols 1032..1087 zero (lanes 8..63)
            int cc = 128 + (lane >> 3);
            A[r*ASTR_ + ((cc ^ key)*8) + (lane & 7)] = 0;
        }
    }
    __syncthreads();

    // ---- GEMM phase (no barriers, 3-deep B pipeline) ----
    f32x4 acc[2][4];
    #pragma unroll
    for (int m = 0; m < 2; m++)
        #pragma unroll
        for (int n = 0; n < 4; n++) acc[m][n] = (f32x4){0.f,0.f,0.f,0.f};

    const uint4* Pw = P + wv*256 + lr*4 + kg;
    int keyA = lr & 7;

#define LOADB(v0,v1,v2,v3,KB) do { \
        const uint4* q_ = Pw + (KB)*1024; \
        v0 = *(const bf16x8*)&q_[0]; \
        v1 = *(const bf16x8*)&q_[64]; \
        v2 = *(const bf16x8*)&q_[128]; \
        v3 = *(const bf16x8*)&q_[192]; \
    } while(0)
#define LDSA0(KB) (*(const bf16x8*)&A[lr*ASTR_      + ((((KB)*4+kg) ^ keyA)*8)])
#define LDSA1(KB) (*(const bf16x8*)&A[(16+lr)*ASTR_ + ((((KB)*4+kg) ^ keyA)*8)])
#define MFMA8(v0,v1,v2,v3,a0_,a1_) do { \
        acc[0][0] = __builtin_amdgcn_mfma_f32_16x16x32_bf16(a0_, v0, acc[0][0],0,0,0); \
        acc[0][1] = __builtin_amdgcn_mfma_f32_16x16x32_bf16(a0_, v1, acc[0][1],0,0,0); \
        acc[0][2] = __builtin_amdgcn_mfma_f32_16x16x32_bf16(a0_, v2, acc[0][2],0,0,0); \
        acc[0][3] = __builtin_amdgcn_mfma_f32_16x16x32_bf16(a0_, v3, acc[0][3],0,0,0); \
        acc[1][0] = __builtin_amdgcn_mfma_f32_16x16x32_bf16(a1_, v0, acc[1][0],0,0,0); \
        acc[1][1] = __builtin_amdgcn_mfma_f32_16x16x32_bf16(a1_, v1, acc[1][1],0,0,0); \
        acc[1][2] = __builtin_amdgcn_mfma_f32_16x16x32_bf16(a1_, v2, acc[1][2],0,0,0); \
        acc[1][3] = __builtin_amdgcn_mfma_f32_16x16x32_bf16(a1_, v3, acc[1][3],0,0,0); \
    } while(0)

    bf16x8 a0,a1,a2,a3, d0,d1,d2,d3, e0,e1,e2,e3;
    LOADB(a0,a1,a2,a3, 0);
    LOADB(d0,d1,d2,d3, 1);
    LOADB(e0,e1,e2,e3, 2);
    for (int kb = 0; kb < 30; kb += 3) {
        bf16x8 af0, af1;
        af0 = LDSA0(kb);   af1 = LDSA1(kb);
        MFMA8(a0,a1,a2,a3, af0, af1);
        LOADB(a0,a1,a2,a3, kb+3);
        af0 = LDSA0(kb+1); af1 = LDSA1(kb+1);
        MFMA8(d0,d1,d2,d3, af0, af1);
        LOADB(d0,d1,d2,d3, kb+4);
        af0 = LDSA0(kb+2); af1 = LDSA1(kb+2);
        MFMA8(e0,e1,e2,e3, af0, af1);
        LOADB(e0,e1,e2,e3, kb+5);
    }
    {
        bf16x8 af0, af1;
        af0 = LDSA0(30); af1 = LDSA1(30);
        MFMA8(a0,a1,a2,a3, af0, af1);
        af0 = LDSA0(31); af1 = LDSA1(31);
        MFMA8(d0,d1,d2,d3, af0, af1);
        af0 = LDSA0(32); af1 = LDSA1(32);
        MFMA8(e0,e1,e2,e3, af0, af1);
    }
#undef LOADB
#undef LDSA0
#undef LDSA1
#undef MFMA8

    // ---- epilogue: gelu + *Wg2, reduce over this wave's 64 cols ----
    float rsum[2][4] = {{0.f,0.f,0.f,0.f},{0.f,0.f,0.f,0.f}};
    #pragma unroll
    for (int n = 0; n < 4; n++) {
        int colg = wv*64 + n*16 + lr;
        float bgv = bg1[colg], w2v = Wg2[colg];
        #pragma unroll
        for (int m = 0; m < 2; m++)
            #pragma unroll
            for (int r = 0; r < 4; r++) {
                float gv = gelu_f(acc[m][n][r] + bgv);
                rsum[m][r] = fmaf(gv, w2v, rsum[m][r]);
            }
    }
    #pragma unroll
    for (int off = 1; off < 16; off <<= 1)
        #pragma unroll
        for (int m = 0; m < 2; m++)
            #pragma unroll
            for (int r = 0; r < 4; r++)
                rsum[m][r] += __shfl_xor(rsum[m][r], off, 64);
    if (lr == 0) {
        #pragma unroll
        for (int m = 0; m < 2; m++)
            #pragma unroll
            for (int r = 0; r < 4; r++)
                red[wv][m*16 + kg*4 + r] = rsum[m][r];
    }
    __syncthreads();
    if (tid < RB5_)
        out[row0 + tid] = red[0][tid] + red[1][tid] + red[2][tid] + red[3][tid] + bg2[0];
}

// ---------------------------------------------------------------------------
extern "C" void kernel_launch(void* const* d_in, const int* in_sizes, int n_in,
                              void* d_out, int out_size, void* d_ws, size_t ws_size,
                              hipStream_t stream)
{
    const float* x    = (const float*)d_in[0];
    const float* t    = (const float*)d_in[1];
    const float* Wt1  = (const float*)d_in[2];
    const float* bt1  = (const float*)d_in[3];
    const float* Wt2  = (const float*)d_in[4];
    const float* bt2  = (const float*)d_in[5];
    const float* Wpf  = (const float*)d_in[6];
    const float* bpf  = (const float*)d_in[7];
    const float* Wpb  = (const float*)d_in[8];
    const float* bpb  = (const float*)d_in[9];
    const float* Wzf  = (const float*)d_in[10];
    const float* bzf  = (const float*)d_in[11];
    const float* Whf  = (const float*)d_in[12];
    const float* bhf  = (const float*)d_in[13];
    const float* Wzb  = (const float*)d_in[14];
    const float* bzb  = (const float*)d_in[15];
    const float* Whb  = (const float*)d_in[16];
    const float* bhb  = (const float*)d_in[17];
    const float* ln_g = (const float*)d_in[18];
    const float* ln_b = (const float*)d_in[19];
    const float* tsc  = (const float*)d_in[20];
    const float* Wg1  = (const float*)d_in[21];
    const float* bg1  = (const float*)d_in[22];
    const float* Wg2  = (const float*)d_in[23];
    const float* bg2  = (const float*)d_in[24];
    float* out = (float*)d_out;

    char* p = (char*)d_ws;
    auto carve = [&](size_t bytes) -> char* {
        char* q = p; p += (bytes + 255) & ~(size_t)255; return q;
    };

    unsigned short* WTf = (unsigned short*)carve((size_t)2*H_*H_*2);
    unsigned short* WTb = (unsigned short*)carve((size_t)2*H_*H_*2);
    uint4*          Pg  = (uint4*)carve((size_t)33*1024*16);

    const size_t perBatch = (size_t)L_*H_*2            // inp
                          + (size_t)L_*NWS_*2*2        // ATF + ATB
                          + (size_t)L_*NT_*4           // tenc
                          + (size_t)CH_*H_*4*3*2;      // carries
    size_t fixedUsed = (size_t)(p - (char*)d_ws) + 64*1024;
    int NB = B_;
    while (NB > 1 && fixedUsed + (size_t)NB*perBatch > ws_size) NB >>= 1;

    unsigned short* inp = (unsigned short*)carve((size_t)NB*L_*H_*2);
    unsigned short* ATF = (unsigned short*)carve((size_t)NB*L_*NWS_*2);
    unsigned short* ATB = (unsigned short*)carve((size_t)NB*L_*NWS_*2);
    float* tenc   = (float*)carve((size_t)NB*L_*NT_*4);
    float* Scar   = (float*)carve((size_t)2*NB*CH_*H_*4);
    float* Pcar   = (float*)carve((size_t)2*NB*CH_*H_*4);
    float* Hstart = (float*)carve((size_t)2*NB*CH_*H_*4);

    {
        dim3 g(H_/32, H_/32);
        kT<<<g, 256, 0, stream>>>(Wzf, WTf,         H_, H_, H_);
        kT<<<g, 256, 0, stream>>>(Whf, WTf + H_*H_, H_, H_, H_);
        kT<<<g, 256, 0, stream>>>(Wzb, WTb,         H_, H_, H_);
        kT<<<g, 256, 0, stream>>>(Whb, WTb + H_*H_, H_, H_, H_);
        kP<<<132, 256, 0, stream>>>(Wg1, Pg);
    }

    for (int b0 = 0; b0 < B_; b0 += NB) {
        int rows = NB * L_;
        int nwg3 = (rows/128) * 8;

        k1_tenc_inp<<<rows/4, 256, 0, stream>>>(
            x + (size_t)b0*L_*2, t + (size_t)b0*L_,
            Wt1, bt1, Wt2, bt2, Wpf, bpf, tenc, inp);
        k3g<<<nwg3, 256, 0, stream>>>(inp, WTf, ATF, nwg3);

        k1_tenc_inp<<<rows/4, 256, 0, stream>>>(
            x + (size_t)b0*L_*2, t + (size_t)b0*L_,
            Wt1, bt1, Wt2, bt2, Wpb, bpb, tenc, inp);
        k3g<<<nwg3, 256, 0, stream>>>(inp, WTb, ATB, nwg3);

        int scanThreads = 2*NB*H_*CH_;
        k4a<<<scanThreads/256, 256, 0, stream>>>(ATF, ATB, bzf, bhf, bzb, bhb,
                                                 Scar, Pcar, NB);
        k4b<<<(2*NB*H_)/256, 256, 0, stream>>>(Scar, Pcar, Hstart, NB);

        k5_fused<<<rows/RB5_, 256, 0, stream>>>(
            ATF, ATB, Hstart, tenc, ln_g, ln_b, tsc,
            Pg, bg1, Wg2, bg2, out + (size_t)b0*L_, NB);
    }
}

// Round 15
// 274.770 us; speedup vs baseline: 1.5635x; 1.0508x over previous
//
#include <hip/hip_runtime.h>
#include <hip/hip_bf16.h>
#include <math.h>

#define B_    16
#define L_    2048
#define H_    512
#define NT_   8
#define OUT_  1032
#define HEAD_ 256
#define CH_   16
#define CL_   (L_/CH_)   // 128
#define NWS_  1152       // AT row stride in shorts (z|h -> S|PP in place)

// k5 A-LDS geometry: 32 rows, 136 chunks of 16B (2176B row), XOR-swizzled
#define ACH_  136
#define ASTR_ (ACH_*8)   // shorts per row = 1088
#define RB5_  32         // rows per k5 block

typedef short bf16x8 __attribute__((ext_vector_type(8)));
typedef float f32x4  __attribute__((ext_vector_type(4)));

__device__ __forceinline__ float b2f(unsigned short u) {
    union { unsigned int u32; float f; } v; v.u32 = ((unsigned int)u) << 16; return v.f;
}
__device__ __forceinline__ unsigned short f2b(float f) {
    __hip_bfloat16 h = __float2bfloat16(f);
    return *reinterpret_cast<unsigned short*>(&h);
}
__device__ __forceinline__ float sigmoid_f(float x) {
    return 1.f / (1.f + exp2f(-1.44269504f * x));
}
__device__ __forceinline__ float tanh_f(float x) {
    float e = exp2f(2.88539008f * x);
    return 1.f - 2.f / (e + 1.f);
}
__device__ __forceinline__ float gelu_f(float g) {
    float u  = 0.70710678118654752f * g;
    float ax = fabsf(u);
    float t  = 1.f / (1.f + 0.3275911f * ax);
    float poly = ((((1.061405429f*t - 1.453152027f)*t + 1.421413741f)*t
                   - 0.284496736f)*t + 0.254829592f)*t;
    float e  = exp2f(-1.44269504f * ax * ax);
    float er = 1.f - poly * e;
    er = (u < 0.f) ? -er : er;
    return 0.5f * g * (1.f + er);
}

// ---------------------------------------------------------------------------
// kT: transpose + f32->bf16. in f32 [R][C] -> out bf16 [C][RP], zero r>=R.
// ---------------------------------------------------------------------------
__global__ __launch_bounds__(256) void kT(const float* __restrict__ in,
                                          unsigned short* __restrict__ out,
                                          int R, int C, int RP)
{
    __shared__ float tile[32][33];
    int c0 = blockIdx.x * 32, r0 = blockIdx.y * 32;
    int tx = threadIdx.x & 31, ty = threadIdx.x >> 5;
    #pragma unroll
    for (int j = 0; j < 32; j += 8) {
        int r = r0 + ty + j, c = c0 + tx;
        tile[ty + j][tx] = (r < R && c < C) ? in[(size_t)r*C + c] : 0.f;
    }
    __syncthreads();
    #pragma unroll
    for (int j = 0; j < 32; j += 8) {
        int c = c0 + ty + j, r = r0 + tx;
        if (c < C && r < RP) out[(size_t)c*RP + r] = f2b(tile[tx][ty + j]);
    }
}

// ---------------------------------------------------------------------------
// kP: pack Wg1 (f32 [OUT_][256]) into MFMA B-fragment chunks, 33 K-blocks.
// ---------------------------------------------------------------------------
__global__ __launch_bounds__(256) void kP(const float* __restrict__ Wg1,
                                          uint4* __restrict__ P)
{
    int idx = blockIdx.x*256 + threadIdx.x;
    if (idx >= 33*1024) return;
    int kb = idx >> 10;
    int rem = idx & 1023;
    int c  = rem >> 2;
    int kg = rem & 3;
    int k0 = kb*32 + kg*8;
    unsigned short o[8];
    #pragma unroll
    for (int j = 0; j < 8; j++) {
        int k = k0 + j;
        o[j] = (k < OUT_) ? f2b(Wg1[(size_t)k*HEAD_ + c]) : (unsigned short)0;
    }
    P[idx] = *(const uint4*)o;
}

// ---------------------------------------------------------------------------
// K1 (both dirs): t_enc MLP + inp_{f,b} = xc @ Wp{f,b} + bp{f,b}. wave-per-row.
// ---------------------------------------------------------------------------
__global__ __launch_bounds__(256) void k1_tenc_inp(
    const float* __restrict__ x, const float* __restrict__ t,
    const float* __restrict__ Wt1, const float* __restrict__ bt1,
    const float* __restrict__ Wt2, const float* __restrict__ bt2,
    const float* __restrict__ Wpf, const float* __restrict__ bpf,
    const float* __restrict__ Wpb, const float* __restrict__ bpb,
    float* __restrict__ t_enc,
    unsigned short* __restrict__ inp_f, unsigned short* __restrict__ inp_b)
{
    int wv = threadIdx.x >> 6, lane = threadIdx.x & 63;
    size_t row = (size_t)blockIdx.x*4 + wv;
    float tv = t[row];
    float r1[NT_], te[NT_];
    #pragma unroll
    for (int k = 0; k < NT_; k++) r1[k] = fmaxf(tv*Wt1[k] + bt1[k], 0.f);
    #pragma unroll
    for (int j = 0; j < NT_; j++) {
        float a = bt2[j];
        #pragma unroll
        for (int k = 0; k < NT_; k++) a = fmaf(r1[k], Wt2[k*NT_+j], a);
        te[j] = a;
    }
    if (lane < NT_) t_enc[row*NT_ + lane] = te[lane];
    float x0 = x[row*2+0], x1 = x[row*2+1];
    int c0 = lane*8;
    float af[8], ab[8];
    #pragma unroll
    for (int j = 0; j < 8; j++) {
        int c = c0 + j;
        af[j] = fmaf(x0, Wpf[c], fmaf(x1, Wpf[H_+c], bpf[c]));
        ab[j] = fmaf(x0, Wpb[c], fmaf(x1, Wpb[H_+c], bpb[c]));
    }
    #pragma unroll
    for (int k = 0; k < NT_; k++) {
        #pragma unroll
        for (int j = 0; j < 8; j++) {
            af[j] = fmaf(te[k], Wpf[(2+k)*H_+c0+j], af[j]);
            ab[j] = fmaf(te[k], Wpb[(2+k)*H_+c0+j], ab[j]);
        }
    }
    unsigned short of[8], ob[8];
    #pragma unroll
    for (int j = 0; j < 8; j++) { of[j] = f2b(af[j]); ob[j] = f2b(ab[j]); }
    *(uint4*)&inp_f[row*H_ + c0] = *(const uint4*)of;
    *(uint4*)&inp_b[row*H_ + c0] = *(const uint4*)ob;
}

// ---------------------------------------------------------------------------
// K3g (both dirs, one dispatch): AT{F,B}[row][0..1023] = inp{f,b} @ [Wz|Wh].
// 128x128 tile, BK=32, 80B-pad LDS, register prefetch, XCD remap.
// Grid = 2 * (rows/128) * 8; dir = tile's high bit.
// ---------------------------------------------------------------------------
__global__ __launch_bounds__(256) void k3g(
    const unsigned short* __restrict__ inpF,
    const unsigned short* __restrict__ inpB,
    const unsigned short* __restrict__ WTf,   // [1024][512] (Wz rows, Wh rows)
    const unsigned short* __restrict__ WTb,
    unsigned short* __restrict__ ATF,
    unsigned short* __restrict__ ATB,
    int nwg, int halfTiles)
{
    __shared__ __align__(16) unsigned short As[128*40];
    __shared__ __align__(16) unsigned short Bs[128*40];
    int tid = threadIdx.x;
    int lane = tid & 63, w = tid >> 6;
    int wm = w >> 1, wn = w & 1;
    int kg = lane >> 4, lr = lane & 15;

    int bid = blockIdx.x;
    int cpx = nwg >> 3;
    int tile = (bid & 7) * cpx + (bid >> 3);
    int dir  = tile >= halfTiles;
    int lt   = dir ? (tile - halfTiles) : tile;
    int row0 = (lt >> 3) * 128;
    int n0   = (lt & 7) * 128;
    const unsigned short* inp = dir ? inpB : inpF;
    const unsigned short* WT  = dir ? WTb : WTf;
    unsigned short* zt_out    = dir ? ATB : ATF;

    f32x4 acc[4][4];
    #pragma unroll
    for (int m = 0; m < 4; m++)
        #pragma unroll
        for (int n = 0; n < 4; n++) acc[m][n] = (f32x4){0.f,0.f,0.f,0.f};

    int ar = tid >> 1, aseg = tid & 1;

    uint4 va0, va1, vb0, vb1;
    {
        const uint4* ga = (const uint4*)&inp[(size_t)(row0+ar)*H_ + aseg*16];
        va0 = ga[0]; va1 = ga[1];
        const uint4* gb = (const uint4*)&WT[(size_t)(n0+ar)*H_ + aseg*16];
        vb0 = gb[0]; vb1 = gb[1];
    }

    for (int k0 = 0; k0 < H_; k0 += 32) {
        __syncthreads();
        *(uint4*)&As[ar*40 + aseg*16]     = va0;
        *(uint4*)&As[ar*40 + aseg*16 + 8] = va1;
        *(uint4*)&Bs[ar*40 + aseg*16]     = vb0;
        *(uint4*)&Bs[ar*40 + aseg*16 + 8] = vb1;
        __syncthreads();
        if (k0 + 32 < H_) {
            const uint4* ga = (const uint4*)&inp[(size_t)(row0+ar)*H_ + k0+32 + aseg*16];
            va0 = ga[0]; va1 = ga[1];
            const uint4* gb = (const uint4*)&WT[(size_t)(n0+ar)*H_ + k0+32 + aseg*16];
            vb0 = gb[0]; vb1 = gb[1];
        }
        bf16x8 af[4], bf[4];
        #pragma unroll
        for (int m = 0; m < 4; m++)
            af[m] = *(const bf16x8*)&As[(wm*64 + m*16 + lr)*40 + kg*8];
        #pragma unroll
        for (int n = 0; n < 4; n++)
            bf[n] = *(const bf16x8*)&Bs[(wn*64 + n*16 + lr)*40 + kg*8];
        #pragma unroll
        for (int m = 0; m < 4; m++)
            #pragma unroll
            for (int n = 0; n < 4; n++)
                acc[m][n] = __builtin_amdgcn_mfma_f32_16x16x32_bf16(af[m], bf[n], acc[m][n], 0, 0, 0);
    }

    #pragma unroll
    for (int m = 0; m < 4; m++)
        #pragma unroll
        for (int n = 0; n < 4; n++) {
            int colg = n0 + wn*64 + n*16 + lr;
            #pragma unroll
            for (int r = 0; r < 4; r++) {
                int rowg = row0 + wm*64 + m*16 + kg*4 + r;
                zt_out[(size_t)rowg*NWS_ + colg] = f2b(acc[m][n][r]);
            }
        }
}

// ---------------------------------------------------------------------------
// K4a: bias + activations + chunked scan pass A, in place on AT rows.
// ---------------------------------------------------------------------------
__global__ __launch_bounds__(256) void k4a(
    unsigned short* __restrict__ ATF, unsigned short* __restrict__ ATB,
    const float* __restrict__ bzf, const float* __restrict__ bhf,
    const float* __restrict__ bzb, const float* __restrict__ bhb,
    float* __restrict__ Scar, float* __restrict__ Pcar, int nb)
{
    int g = blockIdx.x*256 + threadIdx.x;
    int col   = g & (H_-1);
    int chunk = (g >> 9) & (CH_-1);
    int rest  = g >> 13;
    int bb    = rest % nb;
    int dir   = rest / nb;
    unsigned short* AT = dir ? ATB : ATF;
    float bzv = (dir ? bzb : bzf)[col];
    float bhv = (dir ? bhb : bhf)[col];
    size_t base = (size_t)bb * L_ * NWS_ + col;
    float h = 0.f, pp = 1.f;
    if (dir == 0) {
        int lo = chunk * CL_;
        for (int p = 0; p < CL_; p += 8) {
            unsigned short zv[8], hv[8];
            #pragma unroll
            for (int j = 0; j < 8; j++) {
                size_t idx = base + (size_t)(lo+p+j)*NWS_;
                zv[j] = AT[idx]; hv[j] = AT[idx + H_];
            }
            #pragma unroll
            for (int j = 0; j < 8; j++) {
                size_t idx = base + (size_t)(lo+p+j)*NWS_;
                float zg = sigmoid_f(b2f(zv[j]) + bzv);
                float a  = 1.f - zg;
                float bg = zg * tanh_f(b2f(hv[j]) + bhv);
                AT[idx]      = f2b(h);
                AT[idx + H_] = f2b(pp);
                h = fmaf(a, h, bg);
                pp *= a;
            }
        }
    } else {
        int hi = chunk * CL_ + CL_ - 1;
        for (int p = 0; p < CL_; p += 8) {
            unsigned short zv[8], hv[8];
            #pragma unroll
            for (int j = 0; j < 8; j++) {
                size_t idx = base + (size_t)(hi-p-j)*NWS_;
                zv[j] = AT[idx]; hv[j] = AT[idx + H_];
            }
            #pragma unroll
            for (int j = 0; j < 8; j++) {
                size_t idx = base + (size_t)(hi-p-j)*NWS_;
                float zg = sigmoid_f(b2f(zv[j]) + bzv);
                float a  = 1.f - zg;
                float bg = zg * tanh_f(b2f(hv[j]) + bhv);
                AT[idx]      = f2b(h);
                AT[idx + H_] = f2b(pp);
                h = fmaf(a, h, bg);
                pp *= a;
            }
        }
    }
    int ci = ((dir*nb + bb)*CH_ + chunk)*H_ + col;
    Scar[ci] = h; Pcar[ci] = pp;
}

// K4b: chain carries across chunks.
__global__ __launch_bounds__(256) void k4b(
    const float* __restrict__ Scar, const float* __restrict__ Pcar,
    float* __restrict__ Hstart, int nb)
{
    int g = blockIdx.x*256 + threadIdx.x;
    int col  = g & (H_-1);
    int rest = g >> 9;
    int bb   = rest % nb;
    int dir  = rest / nb;
    int baseci = (dir*nb + bb)*CH_;
    float h = 0.f;
    if (dir == 0) {
        for (int c = 0; c < CH_; c++) {
            int ci = (baseci + c)*H_ + col;
            Hstart[ci] = h;
            h = Scar[ci] + Pcar[ci]*h;
        }
    } else {
        for (int c = CH_-1; c >= 0; c--) {
            int ci = (baseci + c)*H_ + col;
            Hstart[ci] = h;
            h = Scar[ci] + Pcar[ci]*h;
        }
    }
}

// ---------------------------------------------------------------------------
// K5 fused: round-14 structure; __launch_bounds__(256,2) so the register
// allocator (up to 256 VGPR at 2 waves/SIMD) KEEPS the rolling LN prefetch
// and 3-deep B pipeline live in registers instead of sinking the loads.
// ---------------------------------------------------------------------------
__global__ __launch_bounds__(256, 2) void k5_fused(
    const unsigned short* __restrict__ ATF, const unsigned short* __restrict__ ATB,
    const float* __restrict__ Hstart,
    const float* __restrict__ tenc,
    const float* __restrict__ ln_g, const float* __restrict__ ln_b,
    const float* __restrict__ tsp,
    const uint4* __restrict__ P,              // [33*1024] packed Wg1 fragments
    const float* __restrict__ bg1, const float* __restrict__ Wg2,
    const float* __restrict__ bg2,
    float* __restrict__ out, int nb)
{
    __shared__ __align__(16) unsigned short A[RB5_*ASTR_];   // 68 KB
    __shared__ float red[4][RB5_];
    int tid = threadIdx.x, lane = tid & 63, wv = tid >> 6;
    int kg = lane >> 4, lr = lane & 15;
    int row0 = blockIdx.x * RB5_;
    float ts = tsp[0];

    int bb    = row0 >> 11;          // / L_
    int chunk = (row0 & (L_-1)) >> 7;
    int cif = (bb*CH_ + chunk)*H_;
    int cib = ((nb + bb)*CH_ + chunk)*H_;
    int c0 = lane*8;
    float4 hfa = *(const float4*)&Hstart[cif + c0];
    float4 hfb = *(const float4*)&Hstart[cif + c0 + 4];
    float4 hba = *(const float4*)&Hstart[cib + c0];
    float4 hbb = *(const float4*)&Hstart[cib + c0 + 4];
    float h0f[8] = {hfa.x,hfa.y,hfa.z,hfa.w,hfb.x,hfb.y,hfb.z,hfb.w};
    float h0b[8] = {hba.x,hba.y,hba.z,hba.w,hbb.x,hbb.y,hbb.z,hbb.w};

    float gf[8], bf_[8], gb_[8], bb_[8];
    #pragma unroll
    for (int j = 0; j < 8; j++) {
        gf[j]  = ln_g[c0+j];     bf_[j] = ln_b[c0+j];
        gb_[j] = ln_g[H_+c0+j];  bb_[j] = ln_b[H_+c0+j];
    }
    float gt = 0.f, bt = 0.f;
    if (lane < NT_) { gt = ln_g[2*H_+lane]; bt = ln_b[2*H_+lane]; }

    // ---- LN phase with rolling-1 row prefetch ----
    size_t rowBase = (size_t)(row0 + wv*8) * NWS_;
    uint4 cSF = *(const uint4*)&ATF[rowBase + c0];
    uint4 cPF = *(const uint4*)&ATF[rowBase + H_ + c0];
    uint4 cSB = *(const uint4*)&ATB[rowBase + c0];
    uint4 cPB = *(const uint4*)&ATB[rowBase + H_ + c0];

    #pragma unroll
    for (int i = 0; i < 8; i++) {
        int r = wv*8 + i;
        size_t row = (size_t)row0 + r;
        uint4 SF = cSF, PF = cPF, SB = cSB, PB = cPB;
        if (i < 7) {
            size_t rb2 = rowBase + (size_t)(i+1)*NWS_;
            cSF = *(const uint4*)&ATF[rb2 + c0];
            cPF = *(const uint4*)&ATF[rb2 + H_ + c0];
            cSB = *(const uint4*)&ATB[rb2 + c0];
            cPB = *(const uint4*)&ATB[rb2 + H_ + c0];
        }
        const unsigned short* sf = (const unsigned short*)&SF;
        const unsigned short* pf = (const unsigned short*)&PF;
        const unsigned short* sb = (const unsigned short*)&SB;
        const unsigned short* pb = (const unsigned short*)&PB;
        float fv[8], bv[8];
        float S = 0.f, Q = 0.f;
        #pragma unroll
        for (int j = 0; j < 8; j++) {
            fv[j] = fmaf(b2f(pf[j]), h0f[j], b2f(sf[j]));
            S += fv[j]; Q += fv[j]*fv[j];
            bv[j] = fmaf(b2f(pb[j]), h0b[j], b2f(sb[j]));
            S += bv[j]; Q += bv[j]*bv[j];
        }
        float tv = 0.f;
        if (lane < NT_) { tv = tenc[row*NT_ + lane]; S += tv; Q += tv*tv; }
        #pragma unroll
        for (int off = 32; off > 0; off >>= 1) {
            S += __shfl_xor(S, off, 64);
            Q += __shfl_xor(Q, off, 64);
        }
        float mu = S * (1.f/1032.f);
        float rs = rsqrtf(Q * (1.f/1032.f) - mu*mu + 1e-5f);
        int key = r & 7;
        unsigned short o[8];
        #pragma unroll
        for (int j = 0; j < 8; j++) o[j] = f2b((fv[j]-mu)*rs*gf[j] + bf_[j]);
        *(uint4*)&A[r*ASTR_ + ((lane ^ key)*8)] = *(const uint4*)o;
        #pragma unroll
        for (int j = 0; j < 8; j++) o[j] = f2b((bv[j]-mu)*rs*gb_[j] + bb_[j]);
        *(uint4*)&A[r*ASTR_ + (((64+lane) ^ key)*8)] = *(const uint4*)o;
        if (lane < NT_) {
            A[r*ASTR_ + ((128 ^ key)*8) + lane] =
                f2b(((tv-mu)*rs*gt + bt) * ts);
        } else {
            int cc = 128 + (lane >> 3);
            A[r*ASTR_ + ((cc ^ key)*8) + (lane & 7)] = 0;
        }
    }
    __syncthreads();

    // ---- GEMM phase (no barriers, 3-deep B pipeline) ----
    f32x4 acc[2][4];
    #pragma unroll
    for (int m = 0; m < 2; m++)
        #pragma unroll
        for (int n = 0; n < 4; n++) acc[m][n] = (f32x4){0.f,0.f,0.f,0.f};

    const uint4* Pw = P + wv*256 + lr*4 + kg;
    int keyA = lr & 7;

#define LOADB(v0,v1,v2,v3,KB) do { \
        const uint4* q_ = Pw + (KB)*1024; \
        v0 = *(const bf16x8*)&q_[0]; \
        v1 = *(const bf16x8*)&q_[64]; \
        v2 = *(const bf16x8*)&q_[128]; \
        v3 = *(const bf16x8*)&q_[192]; \
    } while(0)
#define LDSA0(KB) (*(const bf16x8*)&A[lr*ASTR_      + ((((KB)*4+kg) ^ keyA)*8)])
#define LDSA1(KB) (*(const bf16x8*)&A[(16+lr)*ASTR_ + ((((KB)*4+kg) ^ keyA)*8)])
#define MFMA8(v0,v1,v2,v3,a0_,a1_) do { \
        acc[0][0] = __builtin_amdgcn_mfma_f32_16x16x32_bf16(a0_, v0, acc[0][0],0,0,0); \
        acc[0][1] = __builtin_amdgcn_mfma_f32_16x16x32_bf16(a0_, v1, acc[0][1],0,0,0); \
        acc[0][2] = __builtin_amdgcn_mfma_f32_16x16x32_bf16(a0_, v2, acc[0][2],0,0,0); \
        acc[0][3] = __builtin_amdgcn_mfma_f32_16x16x32_bf16(a0_, v3, acc[0][3],0,0,0); \
        acc[1][0] = __builtin_amdgcn_mfma_f32_16x16x32_bf16(a1_, v0, acc[1][0],0,0,0); \
        acc[1][1] = __builtin_amdgcn_mfma_f32_16x16x32_bf16(a1_, v1, acc[1][1],0,0,0); \
        acc[1][2] = __builtin_amdgcn_mfma_f32_16x16x32_bf16(a1_, v2, acc[1][2],0,0,0); \
        acc[1][3] = __builtin_amdgcn_mfma_f32_16x16x32_bf16(a1_, v3, acc[1][3],0,0,0); \
    } while(0)

    bf16x8 a0,a1,a2,a3, d0,d1,d2,d3, e0,e1,e2,e3;
    LOADB(a0,a1,a2,a3, 0);
    LOADB(d0,d1,d2,d3, 1);
    LOADB(e0,e1,e2,e3, 2);
    for (int kb = 0; kb < 30; kb += 3) {
        bf16x8 af0, af1;
        af0 = LDSA0(kb);   af1 = LDSA1(kb);
        MFMA8(a0,a1,a2,a3, af0, af1);
        LOADB(a0,a1,a2,a3, kb+3);
        af0 = LDSA0(kb+1); af1 = LDSA1(kb+1);
        MFMA8(d0,d1,d2,d3, af0, af1);
        LOADB(d0,d1,d2,d3, kb+4);
        af0 = LDSA0(kb+2); af1 = LDSA1(kb+2);
        MFMA8(e0,e1,e2,e3, af0, af1);
        LOADB(e0,e1,e2,e3, kb+5);
    }
    {
        bf16x8 af0, af1;
        af0 = LDSA0(30); af1 = LDSA1(30);
        MFMA8(a0,a1,a2,a3, af0, af1);
        af0 = LDSA0(31); af1 = LDSA1(31);
        MFMA8(d0,d1,d2,d3, af0, af1);
        af0 = LDSA0(32); af1 = LDSA1(32);
        MFMA8(e0,e1,e2,e3, af0, af1);
    }
#undef LOADB
#undef LDSA0
#undef LDSA1
#undef MFMA8

    // ---- epilogue: gelu + *Wg2, reduce over this wave's 64 cols ----
    float rsum[2][4] = {{0.f,0.f,0.f,0.f},{0.f,0.f,0.f,0.f}};
    #pragma unroll
    for (int n = 0; n < 4; n++) {
        int colg = wv*64 + n*16 + lr;
        float bgv = bg1[colg], w2v = Wg2[colg];
        #pragma unroll
        for (int m = 0; m < 2; m++)
            #pragma unroll
            for (int r = 0; r < 4; r++) {
                float gv = gelu_f(acc[m][n][r] + bgv);
                rsum[m][r] = fmaf(gv, w2v, rsum[m][r]);
            }
    }
    #pragma unroll
    for (int off = 1; off < 16; off <<= 1)
        #pragma unroll
        for (int m = 0; m < 2; m++)
            #pragma unroll
            for (int r = 0; r < 4; r++)
                rsum[m][r] += __shfl_xor(rsum[m][r], off, 64);
    if (lr == 0) {
        #pragma unroll
        for (int m = 0; m < 2; m++)
            #pragma unroll
            for (int r = 0; r < 4; r++)
                red[wv][m*16 + kg*4 + r] = rsum[m][r];
    }
    __syncthreads();
    if (tid < RB5_)
        out[row0 + tid] = red[0][tid] + red[1][tid] + red[2][tid] + red[3][tid] + bg2[0];
}

// ---------------------------------------------------------------------------
extern "C" void kernel_launch(void* const* d_in, const int* in_sizes, int n_in,
                              void* d_out, int out_size, void* d_ws, size_t ws_size,
                              hipStream_t stream)
{
    const float* x    = (const float*)d_in[0];
    const float* t    = (const float*)d_in[1];
    const float* Wt1  = (const float*)d_in[2];
    const float* bt1  = (const float*)d_in[3];
    const float* Wt2  = (const float*)d_in[4];
    const float* bt2  = (const float*)d_in[5];
    const float* Wpf  = (const float*)d_in[6];
    const float* bpf  = (const float*)d_in[7];
    const float* Wpb  = (const float*)d_in[8];
    const float* bpb  = (const float*)d_in[9];
    const float* Wzf  = (const float*)d_in[10];
    const float* bzf  = (const float*)d_in[11];
    const float* Whf  = (const float*)d_in[12];
    const float* bhf  = (const float*)d_in[13];
    const float* Wzb  = (const float*)d_in[14];
    const float* bzb  = (const float*)d_in[15];
    const float* Whb  = (const float*)d_in[16];
    const float* bhb  = (const float*)d_in[17];
    const float* ln_g = (const float*)d_in[18];
    const float* ln_b = (const float*)d_in[19];
    const float* tsc  = (const float*)d_in[20];
    const float* Wg1  = (const float*)d_in[21];
    const float* bg1  = (const float*)d_in[22];
    const float* Wg2  = (const float*)d_in[23];
    const float* bg2  = (const float*)d_in[24];
    float* out = (float*)d_out;

    char* p = (char*)d_ws;
    auto carve = [&](size_t bytes) -> char* {
        char* q = p; p += (bytes + 255) & ~(size_t)255; return q;
    };

    unsigned short* WTf = (unsigned short*)carve((size_t)2*H_*H_*2);
    unsigned short* WTb = (unsigned short*)carve((size_t)2*H_*H_*2);
    uint4*          Pg  = (uint4*)carve((size_t)33*1024*16);

    const size_t perBatch = (size_t)L_*H_*2*2          // inpF + inpB
                          + (size_t)L_*NWS_*2*2        // ATF + ATB
                          + (size_t)L_*NT_*4           // tenc
                          + (size_t)CH_*H_*4*3*2;      // carries
    size_t fixedUsed = (size_t)(p - (char*)d_ws) + 64*1024;
    int NB = B_;
    while (NB > 1 && fixedUsed + (size_t)NB*perBatch > ws_size) NB >>= 1;

    unsigned short* inpF = (unsigned short*)carve((size_t)NB*L_*H_*2);
    unsigned short* inpB = (unsigned short*)carve((size_t)NB*L_*H_*2);
    unsigned short* ATF = (unsigned short*)carve((size_t)NB*L_*NWS_*2);
    unsigned short* ATB = (unsigned short*)carve((size_t)NB*L_*NWS_*2);
    float* tenc   = (float*)carve((size_t)NB*L_*NT_*4);
    float* Scar   = (float*)carve((size_t)2*NB*CH_*H_*4);
    float* Pcar   = (float*)carve((size_t)2*NB*CH_*H_*4);
    float* Hstart = (float*)carve((size_t)2*NB*CH_*H_*4);

    {
        dim3 g(H_/32, H_/32);
        kT<<<g, 256, 0, stream>>>(Wzf, WTf,         H_, H_, H_);
        kT<<<g, 256, 0, stream>>>(Whf, WTf + H_*H_, H_, H_, H_);
        kT<<<g, 256, 0, stream>>>(Wzb, WTb,         H_, H_, H_);
        kT<<<g, 256, 0, stream>>>(Whb, WTb + H_*H_, H_, H_, H_);
        kP<<<132, 256, 0, stream>>>(Wg1, Pg);
    }

    for (int b0 = 0; b0 < B_; b0 += NB) {
        int rows = NB * L_;
        int halfTiles = (rows/128) * 8;
        int nwg3 = 2 * halfTiles;

        k1_tenc_inp<<<rows/4, 256, 0, stream>>>(
            x + (size_t)b0*L_*2, t + (size_t)b0*L_,
            Wt1, bt1, Wt2, bt2, Wpf, bpf, Wpb, bpb,
            tenc, inpF, inpB);

        k3g<<<nwg3, 256, 0, stream>>>(inpF, inpB, WTf, WTb, ATF, ATB,
                                      nwg3, halfTiles);

        int scanThreads = 2*NB*H_*CH_;
        k4a<<<scanThreads/256, 256, 0, stream>>>(ATF, ATB, bzf, bhf, bzb, bhb,
                                                 Scar, Pcar, NB);
        k4b<<<(2*NB*H_)/256, 256, 0, stream>>>(Scar, Pcar, Hstart, NB);

        k5_fused<<<rows/RB5_, 256, 0, stream>>>(
            ATF, ATB, Hstart, tenc, ln_g, ln_b, tsc,
            Pg, bg1, Wg2, bg2, out + (size_t)b0*L_, NB);
    }
}